// Round 8
// baseline (413.964 us; speedup 1.0000x reference)
//
#include <hip/hip_runtime.h>
#include <hip/hip_fp16.h>
#include <cstdint>
#include <cstddef>

#define HD 128

typedef short bf16x8 __attribute__((ext_vector_type(8)));   // 8 bf16 in 4 VGPRs
typedef float f32x4 __attribute__((ext_vector_type(4)));

__device__ __forceinline__ unsigned short f2bf(float f) {
    unsigned int u = __float_as_uint(f);
    u += 0x7fff + ((u >> 16) & 1);          // round-to-nearest-even
    return (unsigned short)(u >> 16);
}
__device__ __forceinline__ float bf2f(unsigned short h) {
    return __uint_as_float(((unsigned int)h) << 16);
}

// DPP butterfly add (VALU pipe) — reduce within each 32-lane half (per head)
template<int CTRL>
__device__ __forceinline__ float dpp_add(float x) {
    int y = __builtin_amdgcn_update_dpp(0, __float_as_int(x), CTRL, 0xF, 0xF, true);
    return x + __int_as_float(y);
}
__device__ __forceinline__ float half_reduce(float x) {
    x = dpp_add<0xB1>(x);    // quad_perm xor1
    x = dpp_add<0x4E>(x);    // quad_perm xor2
    x = dpp_add<0x124>(x);   // row_ror:4
    x = dpp_add<0x128>(x);   // row_ror:8 -> row(16) sums
    x += __shfl_xor(x, 16, 64);  // combine two rows of the 32-half
    return x;
}

// fused dual online-softmax update, logits precomputed
__device__ __forceinline__ void pair_update_s(
    float& m, float& s, float2& acc,
    float lA, float lB,
    float vAx, float vAy, float vBx, float vBy)
{
    float nm = fmaxf(fmaxf(m, lA), lB);
    float sc = __expf(m - nm);
    float eA = __expf(lA - nm);
    float eB = __expf(lB - nm);
    s     = fmaf(s, sc, eA + eB);
    acc.x = fmaf(acc.x, sc, fmaf(eA, vAx, eB * vBx));
    acc.y = fmaf(acc.y, sc, fmaf(eA, vAy, eB * vBy));
    m = nm;
}
__device__ __forceinline__ void single_update_s(
    float& m, float& s, float2& acc,
    float lg, float vx, float vy)
{
    float nm = fmaxf(m, lg);
    float sc = __expf(m - nm);
    float ex = __expf(lg - nm);
    s     = fmaf(s, sc, ex);
    acc.x = fmaf(acc.x, sc, ex * vx);
    acc.y = fmaf(acc.y, sc, ex * vy);
    m = nm;
}

// ---------------- CSR-by-dst build ----------------
__global__ __launch_bounds__(256) void hist_kernel(
    const int* __restrict__ dst, int* __restrict__ cnt, int E)
{
    int e = blockIdx.x * 256 + threadIdx.x;
    if (e < E) atomicAdd(&cnt[dst[e]], 1);
}

// 3-phase hierarchical exclusive scan (512 elems/block in LDS)
__global__ __launch_bounds__(256) void scanA_kernel(
    const int* __restrict__ cnt, int* __restrict__ row_ptr,
    int* __restrict__ bsum, int n)
{
    __shared__ int sdata[256];
    int t = threadIdx.x;
    int base = blockIdx.x * 512 + 2 * t;
    int a = (base < n) ? cnt[base] : 0;
    int b = (base + 1 < n) ? cnt[base + 1] : 0;
    int local = a + b;
    sdata[t] = local;
    __syncthreads();
    #pragma unroll
    for (int off = 1; off < 256; off <<= 1) {
        int val = (t >= off) ? sdata[t - off] : 0;
        __syncthreads();
        sdata[t] += val;
        __syncthreads();
    }
    int excl = sdata[t] - local;
    if (base < n)     row_ptr[base] = excl;
    if (base + 1 < n) row_ptr[base + 1] = excl + a;
    if (t == 255) bsum[blockIdx.x] = sdata[255];
}

__global__ __launch_bounds__(256) void scanB_kernel(
    const int* __restrict__ bsum, int* __restrict__ boff, int B)
{
    __shared__ int sdata[256];
    int t = threadIdx.x;
    int local = (t < B) ? bsum[t] : 0;
    sdata[t] = local;
    __syncthreads();
    #pragma unroll
    for (int off = 1; off < 256; off <<= 1) {
        int val = (t >= off) ? sdata[t - off] : 0;
        __syncthreads();
        sdata[t] += val;
        __syncthreads();
    }
    if (t < B) boff[t] = sdata[t] - local;
}

__global__ __launch_bounds__(256) void scanC_kernel(
    int* __restrict__ row_ptr, int* __restrict__ cursor,
    const int* __restrict__ boff, int n, int E)
{
    int t = threadIdx.x;
    int base = blockIdx.x * 512 + 2 * t;
    int off = boff[blockIdx.x];
    if (base + 1 < n) {
        int2 v = *(int2*)&row_ptr[base];
        v.x += off; v.y += off;
        *(int2*)&row_ptr[base] = v;
        *(int2*)&cursor[base]  = v;
    } else if (base < n) {
        int v = row_ptr[base] + off;
        row_ptr[base] = v; cursor[base] = v;
    }
    if (blockIdx.x == 0 && t == 0) row_ptr[n] = E;
}

__global__ __launch_bounds__(256) void scatter_kernel(
    const int* __restrict__ dst, const int* __restrict__ src,
    const float* __restrict__ eattr, int* __restrict__ cursor,
    int2* __restrict__ epack, int E)
{
    int e = blockIdx.x * 256 + threadIdx.x;
    if (e < E) {
        int pos = atomicAdd(&cursor[dst[e]], 1);
        epack[pos] = make_int2(src[e], __float_as_int(eattr[e]));
    }
}

// ---------------- layer-0 attention, fully fused; scalar-logit trick -----------
__global__ __launch_bounds__(256) void attn0_kernel(
    const float* __restrict__ x,
    const float* __restrict__ Wq, const float* __restrict__ bq,
    const float* __restrict__ Wk, const float* __restrict__ bk,
    const float* __restrict__ Wv, const float* __restrict__ bv,
    const float* __restrict__ We, const float* __restrict__ Ws,
    const float* __restrict__ bs,
    const int2* __restrict__ epack, const int* __restrict__ row_ptr,
    float* __restrict__ out, int n)
{
    int i = blockIdx.x * 4 + (threadIdx.x >> 6);
    if (i >= n) return;
    int l = threadIdx.x & 63;
    int j0 = 2 * l;

    float2 wk0 = *(const float2*)&Wk[j0];
    float2 wk1 = *(const float2*)&Wk[HD + j0];
    float2 wv0 = *(const float2*)&Wv[j0];
    float2 wv1 = *(const float2*)&Wv[HD + j0];
    float2 bk2 = *(const float2*)&bk[j0];
    float2 bv2 = *(const float2*)&bv[j0];
    float2 we  = *(const float2*)&We[j0];

    float x0 = x[2 * i], x1 = x[2 * i + 1];
    float2 wq0 = *(const float2*)&Wq[j0];
    float2 wq1 = *(const float2*)&Wq[HD + j0];
    float2 bq2 = *(const float2*)&bq[j0];
    float2 q;
    q.x = fmaf(x1, wq1.x, fmaf(x0, wq0.x, bq2.x));
    q.y = fmaf(x1, wq1.y, fmaf(x0, wq0.y, bq2.y));

    float c0 = half_reduce(fmaf(q.x, wk0.x, q.y * wk0.y)) * 0.125f;
    float c1 = half_reduce(fmaf(q.x, wk1.x, q.y * wk1.y)) * 0.125f;
    float cb = half_reduce(fmaf(q.x, bk2.x, q.y * bk2.y)) * 0.125f;
    float cw = half_reduce(fmaf(q.x, we.x,  q.y * we.y))  * 0.125f;

    int p0 = __builtin_amdgcn_readfirstlane(row_ptr[i]);
    int p1 = __builtin_amdgcn_readfirstlane(row_ptr[i + 1]);

    float m = -INFINITY, s = 0.f;
    float2 acc = make_float2(0.f, 0.f);

    float2 xs0 = {}, xs1 = {}, xs2 = {}, xs3 = {};
    float ea0 = 0.f, ea1 = 0.f, ea2 = 0.f, ea3 = 0.f;

#define LD0(t, idx) do { if ((idx) < p1) { int2 ep_ = epack[idx]; \
    ea##t = __int_as_float(ep_.y); xs##t = *(const float2*)&x[2 * ep_.x]; } } while (0)

#define LOGIT0(xs, ea) fmaf(ea, cw, fmaf(xs.y, c1, fmaf(xs.x, c0, cb)))
#define VREC(xs, ea, vx, vy) \
    float vx = fmaf(ea, we.x, fmaf(xs.y, wv1.x, fmaf(xs.x, wv0.x, bv2.x))); \
    float vy = fmaf(ea, we.y, fmaf(xs.y, wv1.y, fmaf(xs.x, wv0.y, bv2.y)));

    LD0(0, p0); LD0(1, p0 + 1); LD0(2, p0 + 2); LD0(3, p0 + 3);

    int p = p0;
    for (; p + 3 < p1; p += 4) {
        float2 c0v = xs0, c1v = xs1, c2v = xs2, c3v = xs3;
        float a0 = ea0, a1 = ea1, a2 = ea2, a3 = ea3;
        LD0(0, p + 4); LD0(1, p + 5); LD0(2, p + 6); LD0(3, p + 7);
        { VREC(c0v, a0, vAx, vAy) VREC(c1v, a1, vBx, vBy)
          pair_update_s(m, s, acc, LOGIT0(c0v, a0), LOGIT0(c1v, a1), vAx, vAy, vBx, vBy); }
        { VREC(c2v, a2, vAx, vAy) VREC(c3v, a3, vBx, vBy)
          pair_update_s(m, s, acc, LOGIT0(c2v, a2), LOGIT0(c3v, a3), vAx, vAy, vBx, vBy); }
    }
    int rem = p1 - p;
    if (rem >= 2) {
        VREC(xs0, ea0, vAx, vAy) VREC(xs1, ea1, vBx, vBy)
        pair_update_s(m, s, acc, LOGIT0(xs0, ea0), LOGIT0(xs1, ea1), vAx, vAy, vBx, vBy);
    }
    if (rem == 1) {
        VREC(xs0, ea0, vx, vy)
        single_update_s(m, s, acc, LOGIT0(xs0, ea0), vx, vy);
    } else if (rem == 3) {
        VREC(xs2, ea2, vx, vy)
        single_update_s(m, s, acc, LOGIT0(xs2, ea2), vx, vy);
    }

    float inv = 1.f / (s + 1e-16f);
    float2 ws0 = *(const float2*)&Ws[j0];
    float2 ws1 = *(const float2*)&Ws[HD + j0];
    float2 bs2 = *(const float2*)&bs[j0];
    float sk_x = fmaf(x1, ws1.x, fmaf(x0, ws0.x, bs2.x));
    float sk_y = fmaf(x1, ws1.y, fmaf(x0, ws0.y, bs2.y));
    float2 res;
    res.x = fmaxf(fmaf(acc.x, inv, sk_x), 0.f);
    res.y = fmaxf(fmaf(acc.y, inv, sk_y), 0.f);
    *(float2*)&out[(size_t)i * HD + j0] = res;
}

// ---------------- layer-1 attention: fp16 q/s/kv, depth-4 pipeline --------------
__global__ __launch_bounds__(256) void attn_kernel(
    const __half* __restrict__ qh, const __half* __restrict__ kvh,
    const __half* __restrict__ sh, const float* __restrict__ We,
    const int2* __restrict__ epack, const int* __restrict__ row_ptr,
    float* __restrict__ out, int n)
{
    int i = blockIdx.x * 4 + (threadIdx.x >> 6);
    if (i >= n) return;
    int l = threadIdx.x & 63;
    const int2* kv8 = (const int2*)kvh;   // 8B = (k2l,k2l+1,v2l,v2l+1) fp16
    const __half2* qh2 = (const __half2*)qh;
    const __half2* sh2 = (const __half2*)sh;
    float2 q  = __half22float2(qh2[(size_t)i * 64 + l]);
    float2 we = *(const float2*)&We[2 * l];
    int p0 = __builtin_amdgcn_readfirstlane(row_ptr[i]);
    int p1 = __builtin_amdgcn_readfirstlane(row_ptr[i + 1]);

    float m = -INFINITY, s = 0.f;
    float2 acc = make_float2(0.f, 0.f);

    int2 kv0 = {}, kv1 = {}, kv2 = {}, kv3 = {};
    float ea0 = 0.f, ea1 = 0.f, ea2 = 0.f, ea3 = 0.f;

#define LD1(t, idx) do { if ((idx) < p1) { int2 ep_ = epack[idx]; \
    ea##t = __int_as_float(ep_.y); kv##t = kv8[(size_t)ep_.x * 64 + l]; } } while (0)

#define KVX(raw, ea, kx, ky, vx, vy) \
    float2 kf_##kx = __half22float2(*(const __half2*)&raw.x); \
    float2 vf_##kx = __half22float2(*(const __half2*)&raw.y); \
    float kx = fmaf(ea, we.x, kf_##kx.x), ky = fmaf(ea, we.y, kf_##kx.y); \
    float vx = fmaf(ea, we.x, vf_##kx.x), vy = fmaf(ea, we.y, vf_##kx.y);

    LD1(0, p0); LD1(1, p0 + 1); LD1(2, p0 + 2); LD1(3, p0 + 3);

    int p = p0;
    for (; p + 3 < p1; p += 4) {
        int2 c0 = kv0, c1 = kv1, c2 = kv2, c3 = kv3;
        float a0 = ea0, a1 = ea1, a2 = ea2, a3 = ea3;
        LD1(0, p + 4); LD1(1, p + 5); LD1(2, p + 6); LD1(3, p + 7);
        {
            KVX(c0, a0, kAx, kAy, vAx, vAy)
            KVX(c1, a1, kBx, kBy, vBx, vBy)
            float lA = half_reduce(fmaf(q.x, kAx, q.y * kAy)) * 0.125f;
            float lB = half_reduce(fmaf(q.x, kBx, q.y * kBy)) * 0.125f;
            pair_update_s(m, s, acc, lA, lB, vAx, vAy, vBx, vBy);
        }
        {
            KVX(c2, a2, kAx, kAy, vAx, vAy)
            KVX(c3, a3, kBx, kBy, vBx, vBy)
            float lA = half_reduce(fmaf(q.x, kAx, q.y * kAy)) * 0.125f;
            float lB = half_reduce(fmaf(q.x, kBx, q.y * kBy)) * 0.125f;
            pair_update_s(m, s, acc, lA, lB, vAx, vAy, vBx, vBy);
        }
    }
    int rem = p1 - p;
    if (rem >= 2) {
        KVX(kv0, ea0, kAx, kAy, vAx, vAy)
        KVX(kv1, ea1, kBx, kBy, vBx, vBy)
        float lA = half_reduce(fmaf(q.x, kAx, q.y * kAy)) * 0.125f;
        float lB = half_reduce(fmaf(q.x, kBx, q.y * kBy)) * 0.125f;
        pair_update_s(m, s, acc, lA, lB, vAx, vAy, vBx, vBy);
    }
    if (rem == 1) {
        KVX(kv0, ea0, kx, ky, vx, vy)
        single_update_s(m, s, acc, half_reduce(fmaf(q.x, kx, q.y * ky)) * 0.125f, vx, vy);
    } else if (rem == 3) {
        KVX(kv2, ea2, kx, ky, vx, vy)
        single_update_s(m, s, acc, half_reduce(fmaf(q.x, kx, q.y * ky)) * 0.125f, vx, vy);
    }

    float inv = 1.f / (s + 1e-16f);
    float2 skp = __half22float2(sh2[(size_t)i * 64 + l]);
    float2 res;
    res.x = fmaxf(fmaf(acc.x, inv, skp.x), 0.f);
    res.y = fmaxf(fmaf(acc.y, inv, skp.y), 0.f);
    *(float2*)&out[(size_t)i * HD + 2 * l] = res;
}

// ---------------- W pre-pack: f32 [128,128]x4 -> mfma B-fragment order, bf16 hi/lo ----
__global__ __launch_bounds__(256) void pack_kernel(
    const float* __restrict__ Wq, const float* __restrict__ Wk,
    const float* __restrict__ Wv, const float* __restrict__ Ws,
    const float* __restrict__ bq, const float* __restrict__ bk,
    const float* __restrict__ bv, const float* __restrict__ bs,
    unsigned short* __restrict__ Wph, unsigned short* __restrict__ Wpl,
    float* __restrict__ bias_cat)
{
    int id = blockIdx.x * 256 + threadIdx.x;   // 65536 fragment entries
    if (id < 65536) {
        int j = id & 7, lane = (id >> 3) & 63, ks = (id >> 9) & 3, gnt = id >> 11;
        int k = ks * 32 + (lane >> 4) * 8 + j;
        int ncol = gnt * 16 + (lane & 15);
        int mat = ncol >> 7, d = ncol & 127;
        const float* W = (mat == 0) ? Wq : (mat == 1) ? Wk : (mat == 2) ? Wv : Ws;
        float w = W[k * HD + d];
        unsigned short hi = f2bf(w);
        Wph[id] = hi;
        Wpl[id] = f2bf(w - bf2f(hi));
    }
    if (id < 512) {
        int mat = id >> 7, d = id & 127;
        const float* b = (mat == 0) ? bq : (mat == 1) ? bk : (mat == 2) ? bv : bs;
        bias_cat[id] = b[d];
    }
}

// ---------------- layer-1 linears: split-bf16 MFMA, nt-pipelined B prefetch ------
__global__ __launch_bounds__(256) void lin1_mfma(
    const float* __restrict__ A,
    const unsigned short* __restrict__ Wph, const unsigned short* __restrict__ Wpl,
    const float* __restrict__ bias_cat,
    __half* __restrict__ qh, __half* __restrict__ kvh, __half* __restrict__ sh,
    int n)
{
    __shared__ float As[64 * 132];   // 33 KB
    int tid = threadIdx.x;
    int row0 = blockIdx.x * 64;

    #pragma unroll
    for (int it = 0; it < 8; ++it) {
        int idx = it * 1024 + tid * 4;
        int r = idx >> 7, c = idx & 127;
        float4 av = make_float4(0.f, 0.f, 0.f, 0.f);
        if (row0 + r < n) av = *(const float4*)&A[(size_t)(row0 + r) * HD + c];
        *(float4*)&As[r * 132 + c] = av;
    }
    __syncthreads();

    int wave = tid >> 6, lane = tid & 63;
    int m = lane & 15, quad = lane >> 4;

    bf16x8 ah[4], al[4];
    const float* Arow = &As[(wave * 16 + m) * 132];
    #pragma unroll
    for (int ks = 0; ks < 4; ++ks) {
        float4 x0 = *(const float4*)&Arow[ks * 32 + quad * 8];
        float4 x1 = *(const float4*)&Arow[ks * 32 + quad * 8 + 4];
        float v[8] = {x0.x, x0.y, x0.z, x0.w, x1.x, x1.y, x1.z, x1.w};
        #pragma unroll
        for (int j = 0; j < 8; ++j) {
            unsigned short hi = f2bf(v[j]);
            ah[ks][j] = (short)hi;
            al[ks][j] = (short)f2bf(v[j] - bf2f(hi));
        }
    }

    const bf16x8* PH = (const bf16x8*)Wph;
    const bf16x8* PL = (const bf16x8*)Wpl;
    __half2* qh2  = (__half2*)qh;
    __half2* kvh2 = (__half2*)kvh;
    __half2* sh2  = (__half2*)sh;

    int gnt0 = blockIdx.y * 16;
    bf16x8 bhA[4], blA[4], bhB[4], blB[4];
    #pragma unroll
    for (int ks = 0; ks < 4; ++ks) {
        bhA[ks] = PH[(gnt0 * 4 + ks) * 64 + lane];
        blA[ks] = PL[(gnt0 * 4 + ks) * 64 + lane];
    }

    #pragma unroll 2
    for (int nt = 0; nt < 16; ++nt) {
        int gnt = gnt0 + nt;
        if (nt + 1 < 16) {
            #pragma unroll
            for (int ks = 0; ks < 4; ++ks) {
                bhB[ks] = PH[((gnt + 1) * 4 + ks) * 64 + lane];
                blB[ks] = PL[((gnt + 1) * 4 + ks) * 64 + lane];
            }
        }
        f32x4 acc = {0.f, 0.f, 0.f, 0.f};
        #pragma unroll
        for (int ks = 0; ks < 4; ++ks) {
            acc = __builtin_amdgcn_mfma_f32_16x16x32_bf16(ah[ks], bhA[ks], acc, 0, 0, 0);
            acc = __builtin_amdgcn_mfma_f32_16x16x32_bf16(ah[ks], blA[ks], acc, 0, 0, 0);
            acc = __builtin_amdgcn_mfma_f32_16x16x32_bf16(al[ks], bhA[ks], acc, 0, 0, 0);
        }
        int ocol = gnt * 16 + m;
        int mat = gnt >> 3;               // wave-uniform (0..3)
        int d = ocol & 127;
        float bias = bias_cat[ocol];
        bool evenl = (lane & 1) == 0;     // even m <-> even d
        #pragma unroll
        for (int reg = 0; reg < 4; ++reg) {
            int orow = row0 + wave * 16 + quad * 4 + reg;
            float val = acc[reg] + bias;
            float other = __shfl_xor(val, 1, 64);   // partner dim d^1
            if (orow < n && evenl) {
                __half2 hv = __floats2half2_rn(val, other);
                size_t dp = (size_t)(d >> 1);
                if (mat == 0)      qh2[(size_t)orow * 64 + dp] = hv;
                else if (mat == 1) kvh2[(size_t)orow * 128 + dp * 2] = hv;
                else if (mat == 2) kvh2[(size_t)orow * 128 + dp * 2 + 1] = hv;
                else               sh2[(size_t)orow * 64 + dp] = hv;
            }
        }
        // rotate double-buffer INSIDE the loop (bug fix vs round 7)
        #pragma unroll
        for (int ks = 0; ks < 4; ++ks) { bhA[ks] = bhB[ks]; blA[ks] = blB[ks]; }
    }
}

// ---------------- mean-pool (batch sorted -> run-length partials) ----------------
__global__ __launch_bounds__(128) void pool_kernel(
    const float* __restrict__ h, const int* __restrict__ batch,
    float* __restrict__ gsums, float* __restrict__ gcnt, int n)
{
    __shared__ int sb[64];
    int i0 = blockIdx.x * 64;
    int d = threadIdx.x;
    int iend = i0 + 64; if (iend > n) iend = n;
    int csize = iend - i0;
    if (d < csize) sb[d] = batch[i0 + d];
    __syncthreads();
    if (csize <= 0) return;
    float local = 0.f;
    int cur = sb[0];
    int runc = 0;
    for (int i = i0; i < iend; ++i) {
        int g = sb[i - i0];
        if (g != cur) {
            atomicAdd(&gsums[(size_t)cur * HD + d], local);
            if (d == 0) atomicAdd(&gcnt[cur], (float)runc);
            local = 0.f; runc = 0; cur = g;
        }
        local += h[(size_t)i * HD + d];
        runc++;
    }
    atomicAdd(&gsums[(size_t)cur * HD + d], local);
    if (d == 0) atomicAdd(&gcnt[cur], (float)runc);
}

// ---------------- classifier head: one block per graph ----------------
__global__ __launch_bounds__(128) void cls_kernel(
    const float* __restrict__ gsums, const float* __restrict__ gcnt,
    const float* __restrict__ cW1, const float* __restrict__ cb1,
    const float* __restrict__ cW2, const float* __restrict__ cb2,
    float* __restrict__ out)
{
    __shared__ float g[128];
    __shared__ float t[128];
    int gi = blockIdx.x, j = threadIdx.x;
    float c = fmaxf(gcnt[gi], 1.0f);
    g[j] = gsums[(size_t)gi * HD + j] / c;
    __syncthreads();
    float a = cb1[j];
    for (int k = 0; k < 128; ++k) a = fmaf(g[k], cW1[k * 128 + j], a);
    t[j] = fmaxf(a, 0.f);
    __syncthreads();
    if (j < 30) {
        float a2 = cb2[j];
        for (int k = 0; k < 128; ++k) a2 = fmaf(t[k], cW2[k * 30 + j], a2);
        out[gi * 30 + j] = a2;
    }
}

extern "C" void kernel_launch(void* const* d_in, const int* in_sizes, int n_in,
                              void* d_out, int out_size, void* d_ws, size_t ws_size,
                              hipStream_t stream)
{
    const float* x     = (const float*)d_in[0];
    const int*   ei    = (const int*)d_in[1];
    const float* eattr = (const float*)d_in[2];
    const int*   batch = (const int*)d_in[3];
    const float* l0_Wq = (const float*)d_in[4];
    const float* l0_bq = (const float*)d_in[5];
    const float* l0_Wk = (const float*)d_in[6];
    const float* l0_bk = (const float*)d_in[7];
    const float* l0_Wv = (const float*)d_in[8];
    const float* l0_bv = (const float*)d_in[9];
    const float* l0_We = (const float*)d_in[10];
    const float* l0_Ws = (const float*)d_in[11];
    const float* l0_bs = (const float*)d_in[12];
    const float* l1_Wq = (const float*)d_in[13];
    const float* l1_bq = (const float*)d_in[14];
    const float* l1_Wk = (const float*)d_in[15];
    const float* l1_bk = (const float*)d_in[16];
    const float* l1_Wv = (const float*)d_in[17];
    const float* l1_bv = (const float*)d_in[18];
    const float* l1_We = (const float*)d_in[19];
    const float* l1_Ws = (const float*)d_in[20];
    const float* l1_bs = (const float*)d_in[21];
    const float* cW1   = (const float*)d_in[22];
    const float* cb1   = (const float*)d_in[23];
    const float* cW2   = (const float*)d_in[24];
    const float* cb2   = (const float*)d_in[25];

    int n = in_sizes[0] / 2;     // 50000
    int E = in_sizes[2];         // 800000
    int G = out_size / 30;       // 64
    int B = (n + 511) / 512;     // scan blocks (98)

    size_t nd = (size_t)n * HD;
    float* h      = (float*)d_ws;                 // n*128 f32
    __half* qh    = (__half*)(h + nd);            // n*128 fp16
    __half* sh    = qh + nd;                      // n*128 fp16
    __half* kvh   = sh + nd;                      // n*256 fp16 (interleaved kv pairs)
    float* bias_cat = (float*)(kvh + (size_t)n * 256);         // 512
    unsigned short* Wph = (unsigned short*)(bias_cat + 512);   // 65536
    unsigned short* Wpl = Wph + 65536;                         // 65536
    int2* epack   = (int2*)(Wpl + 65536);         // E (8B-aligned)
    int* cnt      = (int*)(epack + E);            // n
    int* row_ptr  = cnt + n;                      // n+1 (+1 pad)
    int* cursor   = row_ptr + n + 2;              // n
    int* bsum     = cursor + n;                   // B
    int* boff     = bsum + 256;                   // B
    float* gsums  = (float*)(boff + 256);         // G*128
    float* gcnt   = gsums + (size_t)G * HD;       // G

    const int* srcI = ei;
    const int* dstI = ei + E;

    hipMemsetAsync(cnt, 0, (size_t)n * sizeof(int), stream);
    hipMemsetAsync(gsums, 0, ((size_t)G * HD + G) * sizeof(float), stream);

    hist_kernel<<<(E + 255) / 256, 256, 0, stream>>>(dstI, cnt, E);
    scanA_kernel<<<B, 256, 0, stream>>>(cnt, row_ptr, bsum, n);
    scanB_kernel<<<1, 256, 0, stream>>>(bsum, boff, B);
    scanC_kernel<<<B, 256, 0, stream>>>(row_ptr, cursor, boff, n, E);
    scatter_kernel<<<(E + 255) / 256, 256, 0, stream>>>(dstI, srcI, eattr, cursor, epack, E);

    pack_kernel<<<256, 256, 0, stream>>>(l1_Wq, l1_Wk, l1_Wv, l1_Ws,
                                         l1_bq, l1_bk, l1_bv, l1_bs,
                                         Wph, Wpl, bias_cat);

    attn0_kernel<<<(n + 3) / 4, 256, 0, stream>>>(
        x, l0_Wq, l0_bq, l0_Wk, l0_bk, l0_Wv, l0_bv, l0_We, l0_Ws, l0_bs,
        epack, row_ptr, h, n);

    lin1_mfma<<<dim3((n + 63) / 64, 2), 256, 0, stream>>>(
        h, Wph, Wpl, bias_cat, qh, kvh, sh, n);
    attn_kernel<<<(n + 3) / 4, 256, 0, stream>>>(
        qh, kvh, sh, l1_We, epack, row_ptr, h, n);

    pool_kernel<<<(n + 63) / 64, 128, 0, stream>>>(h, batch, gsums, gcnt, n);
    cls_kernel<<<G, 128, 0, stream>>>(gsums, gcnt, cW1, cb1, cW2, cb2, (float*)d_out);
}

// Round 9
// 392.211 us; speedup vs baseline: 1.0555x; 1.0555x over previous
//
#include <hip/hip_runtime.h>
#include <hip/hip_fp16.h>
#include <cstdint>
#include <cstddef>

#define HD 128

typedef short bf16x8 __attribute__((ext_vector_type(8)));   // 8 bf16 in 4 VGPRs
typedef float f32x4 __attribute__((ext_vector_type(4)));

__device__ __forceinline__ unsigned short f2bf(float f) {
    unsigned int u = __float_as_uint(f);
    u += 0x7fff + ((u >> 16) & 1);          // round-to-nearest-even
    return (unsigned short)(u >> 16);
}
__device__ __forceinline__ float bf2f(unsigned short h) {
    return __uint_as_float(((unsigned int)h) << 16);
}

// DPP butterfly add (VALU pipe) — reduce within each 32-lane half (per head)
template<int CTRL>
__device__ __forceinline__ float dpp_add(float x) {
    int y = __builtin_amdgcn_update_dpp(0, __float_as_int(x), CTRL, 0xF, 0xF, true);
    return x + __int_as_float(y);
}
__device__ __forceinline__ float half_reduce(float x) {
    x = dpp_add<0xB1>(x);    // quad_perm xor1
    x = dpp_add<0x4E>(x);    // quad_perm xor2
    x = dpp_add<0x124>(x);   // row_ror:4
    x = dpp_add<0x128>(x);   // row_ror:8 -> row(16) sums
    x += __shfl_xor(x, 16, 64);  // combine two rows of the 32-half
    return x;
}

// fused dual online-softmax update, logits precomputed
__device__ __forceinline__ void pair_update_s(
    float& m, float& s, float2& acc,
    float lA, float lB,
    float vAx, float vAy, float vBx, float vBy)
{
    float nm = fmaxf(fmaxf(m, lA), lB);
    float sc = __expf(m - nm);
    float eA = __expf(lA - nm);
    float eB = __expf(lB - nm);
    s     = fmaf(s, sc, eA + eB);
    acc.x = fmaf(acc.x, sc, fmaf(eA, vAx, eB * vBx));
    acc.y = fmaf(acc.y, sc, fmaf(eA, vAy, eB * vBy));
    m = nm;
}
__device__ __forceinline__ void single_update_s(
    float& m, float& s, float2& acc,
    float lg, float vx, float vy)
{
    float nm = fmaxf(m, lg);
    float sc = __expf(m - nm);
    float ex = __expf(lg - nm);
    s     = fmaf(s, sc, ex);
    acc.x = fmaf(acc.x, sc, ex * vx);
    acc.y = fmaf(acc.y, sc, ex * vy);
    m = nm;
}

// ---------------- CSR-by-dst build ----------------
__global__ __launch_bounds__(256) void hist_kernel(
    const int* __restrict__ dst, int* __restrict__ cnt, int E)
{
    int e = blockIdx.x * 256 + threadIdx.x;
    if (e < E) atomicAdd(&cnt[dst[e]], 1);
}

// 3-phase hierarchical exclusive scan (512 elems/block in LDS)
__global__ __launch_bounds__(256) void scanA_kernel(
    const int* __restrict__ cnt, int* __restrict__ row_ptr,
    int* __restrict__ bsum, int n)
{
    __shared__ int sdata[256];
    int t = threadIdx.x;
    int base = blockIdx.x * 512 + 2 * t;
    int a = (base < n) ? cnt[base] : 0;
    int b = (base + 1 < n) ? cnt[base + 1] : 0;
    int local = a + b;
    sdata[t] = local;
    __syncthreads();
    #pragma unroll
    for (int off = 1; off < 256; off <<= 1) {
        int val = (t >= off) ? sdata[t - off] : 0;
        __syncthreads();
        sdata[t] += val;
        __syncthreads();
    }
    int excl = sdata[t] - local;
    if (base < n)     row_ptr[base] = excl;
    if (base + 1 < n) row_ptr[base + 1] = excl + a;
    if (t == 255) bsum[blockIdx.x] = sdata[255];
}

__global__ __launch_bounds__(256) void scanB_kernel(
    const int* __restrict__ bsum, int* __restrict__ boff, int B)
{
    __shared__ int sdata[256];
    int t = threadIdx.x;
    int local = (t < B) ? bsum[t] : 0;
    sdata[t] = local;
    __syncthreads();
    #pragma unroll
    for (int off = 1; off < 256; off <<= 1) {
        int val = (t >= off) ? sdata[t - off] : 0;
        __syncthreads();
        sdata[t] += val;
        __syncthreads();
    }
    if (t < B) boff[t] = sdata[t] - local;
}

__global__ __launch_bounds__(256) void scanC_kernel(
    int* __restrict__ row_ptr, int* __restrict__ cursor,
    const int* __restrict__ boff, int n, int E)
{
    int t = threadIdx.x;
    int base = blockIdx.x * 512 + 2 * t;
    int off = boff[blockIdx.x];
    if (base + 1 < n) {
        int2 v = *(int2*)&row_ptr[base];
        v.x += off; v.y += off;
        *(int2*)&row_ptr[base] = v;
        *(int2*)&cursor[base]  = v;
    } else if (base < n) {
        int v = row_ptr[base] + off;
        row_ptr[base] = v; cursor[base] = v;
    }
    if (blockIdx.x == 0 && t == 0) row_ptr[n] = E;
}

__global__ __launch_bounds__(256) void scatter_kernel(
    const int* __restrict__ dst, const int* __restrict__ src,
    const float* __restrict__ eattr, int* __restrict__ cursor,
    int2* __restrict__ epack, int E)
{
    int e = blockIdx.x * 256 + threadIdx.x;
    if (e < E) {
        int pos = atomicAdd(&cursor[dst[e]], 1);
        epack[pos] = make_int2(src[e], __float_as_int(eattr[e]));
    }
}

// ---------------- layer-0 attention, fully fused; scalar-logit trick -----------
__global__ __launch_bounds__(256) void attn0_kernel(
    const float* __restrict__ x,
    const float* __restrict__ Wq, const float* __restrict__ bq,
    const float* __restrict__ Wk, const float* __restrict__ bk,
    const float* __restrict__ Wv, const float* __restrict__ bv,
    const float* __restrict__ We, const float* __restrict__ Ws,
    const float* __restrict__ bs,
    const int2* __restrict__ epack, const int* __restrict__ row_ptr,
    float* __restrict__ out, int n)
{
    int i = blockIdx.x * 4 + (threadIdx.x >> 6);
    if (i >= n) return;
    int l = threadIdx.x & 63;
    int j0 = 2 * l;

    float2 wk0 = *(const float2*)&Wk[j0];
    float2 wk1 = *(const float2*)&Wk[HD + j0];
    float2 wv0 = *(const float2*)&Wv[j0];
    float2 wv1 = *(const float2*)&Wv[HD + j0];
    float2 bk2 = *(const float2*)&bk[j0];
    float2 bv2 = *(const float2*)&bv[j0];
    float2 we  = *(const float2*)&We[j0];

    float x0 = x[2 * i], x1 = x[2 * i + 1];
    float2 wq0 = *(const float2*)&Wq[j0];
    float2 wq1 = *(const float2*)&Wq[HD + j0];
    float2 bq2 = *(const float2*)&bq[j0];
    float2 q;
    q.x = fmaf(x1, wq1.x, fmaf(x0, wq0.x, bq2.x));
    q.y = fmaf(x1, wq1.y, fmaf(x0, wq0.y, bq2.y));

    float c0 = half_reduce(fmaf(q.x, wk0.x, q.y * wk0.y)) * 0.125f;
    float c1 = half_reduce(fmaf(q.x, wk1.x, q.y * wk1.y)) * 0.125f;
    float cb = half_reduce(fmaf(q.x, bk2.x, q.y * bk2.y)) * 0.125f;
    float cw = half_reduce(fmaf(q.x, we.x,  q.y * we.y))  * 0.125f;

    int p0 = __builtin_amdgcn_readfirstlane(row_ptr[i]);
    int p1 = __builtin_amdgcn_readfirstlane(row_ptr[i + 1]);

    float m = -INFINITY, s = 0.f;
    float2 acc = make_float2(0.f, 0.f);

    float2 xs0 = {}, xs1 = {}, xs2 = {}, xs3 = {};
    float ea0 = 0.f, ea1 = 0.f, ea2 = 0.f, ea3 = 0.f;

#define LD0(t, idx) do { if ((idx) < p1) { int2 ep_ = epack[idx]; \
    ea##t = __int_as_float(ep_.y); xs##t = *(const float2*)&x[2 * ep_.x]; } } while (0)

#define LOGIT0(xs, ea) fmaf(ea, cw, fmaf(xs.y, c1, fmaf(xs.x, c0, cb)))
#define VREC(xs, ea, vx, vy) \
    float vx = fmaf(ea, we.x, fmaf(xs.y, wv1.x, fmaf(xs.x, wv0.x, bv2.x))); \
    float vy = fmaf(ea, we.y, fmaf(xs.y, wv1.y, fmaf(xs.x, wv0.y, bv2.y)));

    LD0(0, p0); LD0(1, p0 + 1); LD0(2, p0 + 2); LD0(3, p0 + 3);

    int p = p0;
    for (; p + 3 < p1; p += 4) {
        float2 c0v = xs0, c1v = xs1, c2v = xs2, c3v = xs3;
        float a0 = ea0, a1 = ea1, a2 = ea2, a3 = ea3;
        LD0(0, p + 4); LD0(1, p + 5); LD0(2, p + 6); LD0(3, p + 7);
        { VREC(c0v, a0, vAx, vAy) VREC(c1v, a1, vBx, vBy)
          pair_update_s(m, s, acc, LOGIT0(c0v, a0), LOGIT0(c1v, a1), vAx, vAy, vBx, vBy); }
        { VREC(c2v, a2, vAx, vAy) VREC(c3v, a3, vBx, vBy)
          pair_update_s(m, s, acc, LOGIT0(c2v, a2), LOGIT0(c3v, a3), vAx, vAy, vBx, vBy); }
    }
    int rem = p1 - p;
    if (rem >= 2) {
        VREC(xs0, ea0, vAx, vAy) VREC(xs1, ea1, vBx, vBy)
        pair_update_s(m, s, acc, LOGIT0(xs0, ea0), LOGIT0(xs1, ea1), vAx, vAy, vBx, vBy);
    }
    if (rem == 1) {
        VREC(xs0, ea0, vx, vy)
        single_update_s(m, s, acc, LOGIT0(xs0, ea0), vx, vy);
    } else if (rem == 3) {
        VREC(xs2, ea2, vx, vy)
        single_update_s(m, s, acc, LOGIT0(xs2, ea2), vx, vy);
    }

    float inv = 1.f / (s + 1e-16f);
    float2 ws0 = *(const float2*)&Ws[j0];
    float2 ws1 = *(const float2*)&Ws[HD + j0];
    float2 bs2 = *(const float2*)&bs[j0];
    float sk_x = fmaf(x1, ws1.x, fmaf(x0, ws0.x, bs2.x));
    float sk_y = fmaf(x1, ws1.y, fmaf(x0, ws0.y, bs2.y));
    float2 res;
    res.x = fmaxf(fmaf(acc.x, inv, sk_x), 0.f);
    res.y = fmaxf(fmaf(acc.y, inv, sk_y), 0.f);
    *(float2*)&out[(size_t)i * HD + j0] = res;
}

// ---------------- layer-1 attention: fp16 q/s/kv, depth-4 pipeline --------------
__global__ __launch_bounds__(256) void attn_kernel(
    const __half* __restrict__ qh, const __half* __restrict__ kvh,
    const __half* __restrict__ sh, const float* __restrict__ We,
    const int2* __restrict__ epack, const int* __restrict__ row_ptr,
    float* __restrict__ out, int n)
{
    int i = blockIdx.x * 4 + (threadIdx.x >> 6);
    if (i >= n) return;
    int l = threadIdx.x & 63;
    const int2* kv8 = (const int2*)kvh;   // 8B = (k2l,k2l+1,v2l,v2l+1) fp16
    const __half2* qh2 = (const __half2*)qh;
    const __half2* sh2 = (const __half2*)sh;
    float2 q  = __half22float2(qh2[(size_t)i * 64 + l]);
    float2 we = *(const float2*)&We[2 * l];
    int p0 = __builtin_amdgcn_readfirstlane(row_ptr[i]);
    int p1 = __builtin_amdgcn_readfirstlane(row_ptr[i + 1]);

    float m = -INFINITY, s = 0.f;
    float2 acc = make_float2(0.f, 0.f);

    int2 kv0 = {}, kv1 = {}, kv2 = {}, kv3 = {};
    float ea0 = 0.f, ea1 = 0.f, ea2 = 0.f, ea3 = 0.f;

#define LD1(t, idx) do { if ((idx) < p1) { int2 ep_ = epack[idx]; \
    ea##t = __int_as_float(ep_.y); kv##t = kv8[(size_t)ep_.x * 64 + l]; } } while (0)

#define KVX(raw, ea, kx, ky, vx, vy) \
    float2 kf_##kx = __half22float2(*(const __half2*)&raw.x); \
    float2 vf_##kx = __half22float2(*(const __half2*)&raw.y); \
    float kx = fmaf(ea, we.x, kf_##kx.x), ky = fmaf(ea, we.y, kf_##kx.y); \
    float vx = fmaf(ea, we.x, vf_##kx.x), vy = fmaf(ea, we.y, vf_##kx.y);

    LD1(0, p0); LD1(1, p0 + 1); LD1(2, p0 + 2); LD1(3, p0 + 3);

    int p = p0;
    for (; p + 3 < p1; p += 4) {
        int2 c0 = kv0, c1 = kv1, c2 = kv2, c3 = kv3;
        float a0 = ea0, a1 = ea1, a2 = ea2, a3 = ea3;
        LD1(0, p + 4); LD1(1, p + 5); LD1(2, p + 6); LD1(3, p + 7);
        {
            KVX(c0, a0, kAx, kAy, vAx, vAy)
            KVX(c1, a1, kBx, kBy, vBx, vBy)
            float lA = half_reduce(fmaf(q.x, kAx, q.y * kAy)) * 0.125f;
            float lB = half_reduce(fmaf(q.x, kBx, q.y * kBy)) * 0.125f;
            pair_update_s(m, s, acc, lA, lB, vAx, vAy, vBx, vBy);
        }
        {
            KVX(c2, a2, kAx, kAy, vAx, vAy)
            KVX(c3, a3, kBx, kBy, vBx, vBy)
            float lA = half_reduce(fmaf(q.x, kAx, q.y * kAy)) * 0.125f;
            float lB = half_reduce(fmaf(q.x, kBx, q.y * kBy)) * 0.125f;
            pair_update_s(m, s, acc, lA, lB, vAx, vAy, vBx, vBy);
        }
    }
    int rem = p1 - p;
    if (rem >= 2) {
        KVX(kv0, ea0, kAx, kAy, vAx, vAy)
        KVX(kv1, ea1, kBx, kBy, vBx, vBy)
        float lA = half_reduce(fmaf(q.x, kAx, q.y * kAy)) * 0.125f;
        float lB = half_reduce(fmaf(q.x, kBx, q.y * kBy)) * 0.125f;
        pair_update_s(m, s, acc, lA, lB, vAx, vAy, vBx, vBy);
    }
    if (rem == 1) {
        KVX(kv0, ea0, kx, ky, vx, vy)
        single_update_s(m, s, acc, half_reduce(fmaf(q.x, kx, q.y * ky)) * 0.125f, vx, vy);
    } else if (rem == 3) {
        KVX(kv2, ea2, kx, ky, vx, vy)
        single_update_s(m, s, acc, half_reduce(fmaf(q.x, kx, q.y * ky)) * 0.125f, vx, vy);
    }

    float inv = 1.f / (s + 1e-16f);
    float2 skp = __half22float2(sh2[(size_t)i * 64 + l]);
    float2 res;
    res.x = fmaxf(fmaf(acc.x, inv, skp.x), 0.f);
    res.y = fmaxf(fmaf(acc.y, inv, skp.y), 0.f);
    *(float2*)&out[(size_t)i * HD + 2 * l] = res;
}

// ---------------- W pre-pack: f32 [128,128]x4 -> mfma B-fragment order, bf16 hi/lo ----
__global__ __launch_bounds__(256) void pack_kernel(
    const float* __restrict__ Wq, const float* __restrict__ Wk,
    const float* __restrict__ Wv, const float* __restrict__ Ws,
    const float* __restrict__ bq, const float* __restrict__ bk,
    const float* __restrict__ bv, const float* __restrict__ bs,
    unsigned short* __restrict__ Wph, unsigned short* __restrict__ Wpl,
    float* __restrict__ bias_cat)
{
    int id = blockIdx.x * 256 + threadIdx.x;   // 65536 fragment entries
    if (id < 65536) {
        int j = id & 7, lane = (id >> 3) & 63, ks = (id >> 9) & 3, gnt = id >> 11;
        int k = ks * 32 + (lane >> 4) * 8 + j;
        int ncol = gnt * 16 + (lane & 15);
        int mat = ncol >> 7, d = ncol & 127;
        const float* W = (mat == 0) ? Wq : (mat == 1) ? Wk : (mat == 2) ? Wv : Ws;
        float w = W[k * HD + d];
        unsigned short hi = f2bf(w);
        Wph[id] = hi;
        Wpl[id] = f2bf(w - bf2f(hi));
    }
    if (id < 512) {
        int mat = id >> 7, d = id & 127;
        const float* b = (mat == 0) ? bq : (mat == 1) ? bk : (mat == 2) ? bv : bs;
        bias_cat[id] = b[d];
    }
}

// ---------------- layer-1 linears: split-bf16 MFMA, 128 rows/block --------------
// blockIdx.y = 0 -> mats q,s (gnt 0..7, 24..31): direct half2 stores (rows block-private)
// blockIdx.y = 1 -> mats k,v (gnt 8..23): LDS-staged kv tile, coalesced f4 flush
//   (k and v of the same kvh line now come from the SAME block -> no cross-block lines)
__global__ __launch_bounds__(256) void lin1_mfma(
    const float* __restrict__ A,
    const unsigned short* __restrict__ Wph, const unsigned short* __restrict__ Wpl,
    const float* __restrict__ bias_cat,
    __half* __restrict__ qh, __half* __restrict__ kvh, __half* __restrict__ sh,
    int n)
{
    __shared__ float As[128 * 128];   // 64 KB, XOR-swizzled; reused as kv out-stage (y==1)
    int tid = threadIdx.x;
    int row0 = blockIdx.x * 128;
    int yb = blockIdx.y;

    // stage A: float4 with XOR swizzle on f4-slot (slot' = slot ^ (r&7))
    #pragma unroll
    for (int it = 0; it < 16; ++it) {
        int idx = (it * 256 + tid) * 4;
        int r = idx >> 7, c = idx & 127;
        float4 av = make_float4(0.f, 0.f, 0.f, 0.f);
        if (row0 + r < n) av = *(const float4*)&A[(size_t)(row0 + r) * HD + c];
        int sl = (c >> 2) ^ (r & 7);
        *(float4*)&As[r * 128 + sl * 4] = av;
    }
    __syncthreads();

    int wave = tid >> 6, lane = tid & 63;
    int m = lane & 15, quad = lane >> 4;

    // fragments for two 16-row subgroups per wave
    bf16x8 ah[2][4], al[2][4];
    #pragma unroll
    for (int sub = 0; sub < 2; ++sub) {
        int r = wave * 32 + sub * 16 + m;
        const float* base = &As[r * 128];
        int sw = r & 7;
        #pragma unroll
        for (int ks = 0; ks < 4; ++ks) {
            int i40 = (ks * 8 + quad * 2) ^ sw;
            int i41 = (ks * 8 + quad * 2 + 1) ^ sw;
            float4 x0 = *(const float4*)&base[i40 * 4];
            float4 x1 = *(const float4*)&base[i41 * 4];
            float v[8] = {x0.x, x0.y, x0.z, x0.w, x1.x, x1.y, x1.z, x1.w};
            #pragma unroll
            for (int j = 0; j < 8; ++j) {
                unsigned short hi = f2bf(v[j]);
                ah[sub][ks][j] = (short)hi;
                al[sub][ks][j] = (short)f2bf(v[j] - bf2f(hi));
            }
        }
    }
    __syncthreads();   // As now dead -> reusable as kv out-stage

    const bf16x8* PH = (const bf16x8*)Wph;
    const bf16x8* PL = (const bf16x8*)Wpl;
    __half2* qh2 = (__half2*)qh;
    __half2* sh2 = (__half2*)sh;
    __half*  kvS = (__half*)As;       // y==1: 128 rows x 256 halfs = 64 KB

    // gnt mapping: y=0 -> {0..7, 24..31} (q,s); y=1 -> {8..23} (k,v)
    #define GNT_OF(nt) ((yb == 0) ? (((nt) < 8) ? (nt) : (nt) + 16) : (nt) + 8)

    bf16x8 bhA[4], blA[4], bhB[4], blB[4];
    {
        int g0 = GNT_OF(0);
        #pragma unroll
        for (int ks = 0; ks < 4; ++ks) {
            bhA[ks] = PH[(g0 * 4 + ks) * 64 + lane];
            blA[ks] = PL[(g0 * 4 + ks) * 64 + lane];
        }
    }

    for (int nt = 0; nt < 16; ++nt) {
        int gnt = GNT_OF(nt);
        if (nt + 1 < 16) {
            int g2 = GNT_OF(nt + 1);
            #pragma unroll
            for (int ks = 0; ks < 4; ++ks) {
                bhB[ks] = PH[(g2 * 4 + ks) * 64 + lane];
                blB[ks] = PL[(g2 * 4 + ks) * 64 + lane];
            }
        }
        f32x4 acc0 = {0.f, 0.f, 0.f, 0.f};
        f32x4 acc1 = {0.f, 0.f, 0.f, 0.f};
        #pragma unroll
        for (int ks = 0; ks < 4; ++ks) {
            acc0 = __builtin_amdgcn_mfma_f32_16x16x32_bf16(ah[0][ks], bhA[ks], acc0, 0, 0, 0);
            acc1 = __builtin_amdgcn_mfma_f32_16x16x32_bf16(ah[1][ks], bhA[ks], acc1, 0, 0, 0);
            acc0 = __builtin_amdgcn_mfma_f32_16x16x32_bf16(ah[0][ks], blA[ks], acc0, 0, 0, 0);
            acc1 = __builtin_amdgcn_mfma_f32_16x16x32_bf16(ah[1][ks], blA[ks], acc1, 0, 0, 0);
            acc0 = __builtin_amdgcn_mfma_f32_16x16x32_bf16(al[0][ks], bhA[ks], acc0, 0, 0, 0);
            acc1 = __builtin_amdgcn_mfma_f32_16x16x32_bf16(al[1][ks], bhA[ks], acc1, 0, 0, 0);
        }
        int ocol = gnt * 16 + m;
        int d = ocol & 127;
        float bias = bias_cat[ocol];
        if (yb == 0) {
            __half2* dst = (gnt < 8) ? qh2 : sh2;
            bool evenl = (m & 1) == 0;
            #pragma unroll
            for (int sub = 0; sub < 2; ++sub) {
                f32x4 acc = sub ? acc1 : acc0;
                #pragma unroll
                for (int reg = 0; reg < 4; ++reg) {
                    int orow = row0 + wave * 32 + sub * 16 + quad * 4 + reg;
                    float val = acc[reg] + bias;
                    float other = __shfl_xor(val, 1, 64);
                    if (orow < n && evenl)
                        dst[(size_t)orow * 64 + (d >> 1)] = __floats2half2_rn(val, other);
                }
            }
        } else {
            int slot = 4 * (d >> 1) + (d & 1) + ((gnt >= 16) ? 2 : 0);
            #pragma unroll
            for (int sub = 0; sub < 2; ++sub) {
                f32x4 acc = sub ? acc1 : acc0;
                #pragma unroll
                for (int reg = 0; reg < 4; ++reg) {
                    int row_l = wave * 32 + sub * 16 + quad * 4 + reg;
                    kvS[row_l * 256 + slot] = __float2half(acc[reg] + bias);
                }
            }
        }
        #pragma unroll
        for (int ks = 0; ks < 4; ++ks) { bhA[ks] = bhB[ks]; blA[ks] = blB[ks]; }
    }

    if (yb == 1) {
        __syncthreads();
        const float4* kvS4 = (const float4*)kvS;
        float4* kvh4 = (float4*)kvh;
        #pragma unroll
        for (int it = 0; it < 16; ++it) {
            int idx = it * 256 + tid;
            int row = idx >> 5, c4 = idx & 31;     // kvh row = 512 B = 32 f4
            if (row0 + row < n)
                kvh4[(size_t)(row0 + row) * 32 + c4] = kvS4[row * 32 + c4];
        }
    }
    #undef GNT_OF
}

// ---------------- mean-pool (batch sorted -> run-length partials) ----------------
__global__ __launch_bounds__(128) void pool_kernel(
    const float* __restrict__ h, const int* __restrict__ batch,
    float* __restrict__ gsums, float* __restrict__ gcnt, int n)
{
    __shared__ int sb[64];
    int i0 = blockIdx.x * 64;
    int d = threadIdx.x;
    int iend = i0 + 64; if (iend > n) iend = n;
    int csize = iend - i0;
    if (d < csize) sb[d] = batch[i0 + d];
    __syncthreads();
    if (csize <= 0) return;
    float local = 0.f;
    int cur = sb[0];
    int runc = 0;
    for (int i = i0; i < iend; ++i) {
        int g = sb[i - i0];
        if (g != cur) {
            atomicAdd(&gsums[(size_t)cur * HD + d], local);
            if (d == 0) atomicAdd(&gcnt[cur], (float)runc);
            local = 0.f; runc = 0; cur = g;
        }
        local += h[(size_t)i * HD + d];
        runc++;
    }
    atomicAdd(&gsums[(size_t)cur * HD + d], local);
    if (d == 0) atomicAdd(&gcnt[cur], (float)runc);
}

// ---------------- classifier head: one block per graph ----------------
__global__ __launch_bounds__(128) void cls_kernel(
    const float* __restrict__ gsums, const float* __restrict__ gcnt,
    const float* __restrict__ cW1, const float* __restrict__ cb1,
    const float* __restrict__ cW2, const float* __restrict__ cb2,
    float* __restrict__ out)
{
    __shared__ float g[128];
    __shared__ float t[128];
    int gi = blockIdx.x, j = threadIdx.x;
    float c = fmaxf(gcnt[gi], 1.0f);
    g[j] = gsums[(size_t)gi * HD + j] / c;
    __syncthreads();
    float a = cb1[j];
    for (int k = 0; k < 128; ++k) a = fmaf(g[k], cW1[k * 128 + j], a);
    t[j] = fmaxf(a, 0.f);
    __syncthreads();
    if (j < 30) {
        float a2 = cb2[j];
        for (int k = 0; k < 128; ++k) a2 = fmaf(t[k], cW2[k * 30 + j], a2);
        out[gi * 30 + j] = a2;
    }
}

extern "C" void kernel_launch(void* const* d_in, const int* in_sizes, int n_in,
                              void* d_out, int out_size, void* d_ws, size_t ws_size,
                              hipStream_t stream)
{
    const float* x     = (const float*)d_in[0];
    const int*   ei    = (const int*)d_in[1];
    const float* eattr = (const float*)d_in[2];
    const int*   batch = (const int*)d_in[3];
    const float* l0_Wq = (const float*)d_in[4];
    const float* l0_bq = (const float*)d_in[5];
    const float* l0_Wk = (const float*)d_in[6];
    const float* l0_bk = (const float*)d_in[7];
    const float* l0_Wv = (const float*)d_in[8];
    const float* l0_bv = (const float*)d_in[9];
    const float* l0_We = (const float*)d_in[10];
    const float* l0_Ws = (const float*)d_in[11];
    const float* l0_bs = (const float*)d_in[12];
    const float* l1_Wq = (const float*)d_in[13];
    const float* l1_bq = (const float*)d_in[14];
    const float* l1_Wk = (const float*)d_in[15];
    const float* l1_bk = (const float*)d_in[16];
    const float* l1_Wv = (const float*)d_in[17];
    const float* l1_bv = (const float*)d_in[18];
    const float* l1_We = (const float*)d_in[19];
    const float* l1_Ws = (const float*)d_in[20];
    const float* l1_bs = (const float*)d_in[21];
    const float* cW1   = (const float*)d_in[22];
    const float* cb1   = (const float*)d_in[23];
    const float* cW2   = (const float*)d_in[24];
    const float* cb2   = (const float*)d_in[25];

    int n = in_sizes[0] / 2;     // 50000
    int E = in_sizes[2];         // 800000
    int G = out_size / 30;       // 64
    int B = (n + 511) / 512;     // scan blocks (98)

    size_t nd = (size_t)n * HD;
    float* h      = (float*)d_ws;                 // n*128 f32
    __half* qh    = (__half*)(h + nd);            // n*128 fp16
    __half* sh    = qh + nd;                      // n*128 fp16
    __half* kvh   = sh + nd;                      // n*256 fp16 (interleaved kv pairs)
    float* bias_cat = (float*)(kvh + (size_t)n * 256);         // 512
    unsigned short* Wph = (unsigned short*)(bias_cat + 512);   // 65536
    unsigned short* Wpl = Wph + 65536;                         // 65536
    int2* epack   = (int2*)(Wpl + 65536);         // E (8B-aligned)
    int* cnt      = (int*)(epack + E);            // n
    int* row_ptr  = cnt + n;                      // n+1 (+1 pad)
    int* cursor   = row_ptr + n + 2;              // n
    int* bsum     = cursor + n;                   // B
    int* boff     = bsum + 256;                   // B
    float* gsums  = (float*)(boff + 256);         // G*128
    float* gcnt   = gsums + (size_t)G * HD;       // G

    const int* srcI = ei;
    const int* dstI = ei + E;

    hipMemsetAsync(cnt, 0, (size_t)n * sizeof(int), stream);
    hipMemsetAsync(gsums, 0, ((size_t)G * HD + G) * sizeof(float), stream);

    hist_kernel<<<(E + 255) / 256, 256, 0, stream>>>(dstI, cnt, E);
    scanA_kernel<<<B, 256, 0, stream>>>(cnt, row_ptr, bsum, n);
    scanB_kernel<<<1, 256, 0, stream>>>(bsum, boff, B);
    scanC_kernel<<<B, 256, 0, stream>>>(row_ptr, cursor, boff, n, E);
    scatter_kernel<<<(E + 255) / 256, 256, 0, stream>>>(dstI, srcI, eattr, cursor, epack, E);

    pack_kernel<<<256, 256, 0, stream>>>(l1_Wq, l1_Wk, l1_Wv, l1_Ws,
                                         l1_bq, l1_bk, l1_bv, l1_bs,
                                         Wph, Wpl, bias_cat);

    attn0_kernel<<<(n + 3) / 4, 256, 0, stream>>>(
        x, l0_Wq, l0_bq, l0_Wk, l0_bk, l0_Wv, l0_bv, l0_We, l0_Ws, l0_bs,
        epack, row_ptr, h, n);

    lin1_mfma<<<dim3((n + 127) / 128, 2), 256, 0, stream>>>(
        h, Wph, Wpl, bias_cat, qh, kvh, sh, n);
    attn_kernel<<<(n + 3) / 4, 256, 0, stream>>>(
        qh, kvh, sh, l1_We, epack, row_ptr, h, n);

    pool_kernel<<<(n + 63) / 64, 128, 0, stream>>>(h, batch, gsums, gcnt, n);
    cls_kernel<<<G, 128, 0, stream>>>(gsums, gcnt, cW1, cb1, cW2, cb2, (float*)d_out);
}

// Round 10
// 374.246 us; speedup vs baseline: 1.1061x; 1.0480x over previous
//
#include <hip/hip_runtime.h>
#include <hip/hip_fp16.h>
#include <cstdint>
#include <cstddef>

#define HD 128

typedef short bf16x8 __attribute__((ext_vector_type(8)));   // 8 bf16 in 4 VGPRs
typedef float f32x4 __attribute__((ext_vector_type(4)));

__device__ __forceinline__ unsigned short f2bf(float f) {
    unsigned int u = __float_as_uint(f);
    u += 0x7fff + ((u >> 16) & 1);          // round-to-nearest-even
    return (unsigned short)(u >> 16);
}
__device__ __forceinline__ float bf2f(unsigned short h) {
    return __uint_as_float(((unsigned int)h) << 16);
}

// DPP butterfly add (VALU pipe) — reduce within each 32-lane half (per head)
template<int CTRL>
__device__ __forceinline__ float dpp_add(float x) {
    int y = __builtin_amdgcn_update_dpp(0, __float_as_int(x), CTRL, 0xF, 0xF, true);
    return x + __int_as_float(y);
}
__device__ __forceinline__ float half_reduce(float x) {
    x = dpp_add<0xB1>(x);    // quad_perm xor1
    x = dpp_add<0x4E>(x);    // quad_perm xor2
    x = dpp_add<0x124>(x);   // row_ror:4
    x = dpp_add<0x128>(x);   // row_ror:8 -> row(16) sums
    x += __shfl_xor(x, 16, 64);  // combine two rows of the 32-half
    return x;
}
__device__ __forceinline__ float wave_reduce(float x) {
    x = half_reduce(x);
    x += __shfl_xor(x, 32, 64);
    return x;
}

// fused dual online-softmax update, logits precomputed
__device__ __forceinline__ void pair_update_s(
    float& m, float& s, float2& acc,
    float lA, float lB,
    float vAx, float vAy, float vBx, float vBy)
{
    float nm = fmaxf(fmaxf(m, lA), lB);
    float sc = __expf(m - nm);
    float eA = __expf(lA - nm);
    float eB = __expf(lB - nm);
    s     = fmaf(s, sc, eA + eB);
    acc.x = fmaf(acc.x, sc, fmaf(eA, vAx, eB * vBx));
    acc.y = fmaf(acc.y, sc, fmaf(eA, vAy, eB * vBy));
    m = nm;
}
__device__ __forceinline__ void single_update_s(
    float& m, float& s, float2& acc,
    float lg, float vx, float vy)
{
    float nm = fmaxf(m, lg);
    float sc = __expf(m - nm);
    float ex = __expf(lg - nm);
    s     = fmaf(s, sc, ex);
    acc.x = fmaf(acc.x, sc, ex * vx);
    acc.y = fmaf(acc.y, sc, ex * vy);
    m = nm;
}

// ---------------- CSR-by-dst build ----------------
__global__ __launch_bounds__(256) void hist_kernel(
    const int* __restrict__ dst, int* __restrict__ cnt, int E)
{
    int e = blockIdx.x * 256 + threadIdx.x;
    if (e < E) atomicAdd(&cnt[dst[e]], 1);
}

// 3-phase hierarchical exclusive scan (512 elems/block in LDS)
__global__ __launch_bounds__(256) void scanA_kernel(
    const int* __restrict__ cnt, int* __restrict__ row_ptr,
    int* __restrict__ bsum, int n)
{
    __shared__ int sdata[256];
    int t = threadIdx.x;
    int base = blockIdx.x * 512 + 2 * t;
    int a = (base < n) ? cnt[base] : 0;
    int b = (base + 1 < n) ? cnt[base + 1] : 0;
    int local = a + b;
    sdata[t] = local;
    __syncthreads();
    #pragma unroll
    for (int off = 1; off < 256; off <<= 1) {
        int val = (t >= off) ? sdata[t - off] : 0;
        __syncthreads();
        sdata[t] += val;
        __syncthreads();
    }
    int excl = sdata[t] - local;
    if (base < n)     row_ptr[base] = excl;
    if (base + 1 < n) row_ptr[base + 1] = excl + a;
    if (t == 255) bsum[blockIdx.x] = sdata[255];
}

__global__ __launch_bounds__(256) void scanB_kernel(
    const int* __restrict__ bsum, int* __restrict__ boff, int B)
{
    __shared__ int sdata[256];
    int t = threadIdx.x;
    int local = (t < B) ? bsum[t] : 0;
    sdata[t] = local;
    __syncthreads();
    #pragma unroll
    for (int off = 1; off < 256; off <<= 1) {
        int val = (t >= off) ? sdata[t - off] : 0;
        __syncthreads();
        sdata[t] += val;
        __syncthreads();
    }
    if (t < B) boff[t] = sdata[t] - local;
}

__global__ __launch_bounds__(256) void scanC_kernel(
    int* __restrict__ row_ptr, int* __restrict__ cursor,
    const int* __restrict__ boff, int n, int E)
{
    int t = threadIdx.x;
    int base = blockIdx.x * 512 + 2 * t;
    int off = boff[blockIdx.x];
    if (base + 1 < n) {
        int2 v = *(int2*)&row_ptr[base];
        v.x += off; v.y += off;
        *(int2*)&row_ptr[base] = v;
        *(int2*)&cursor[base]  = v;
    } else if (base < n) {
        int v = row_ptr[base] + off;
        row_ptr[base] = v; cursor[base] = v;
    }
    if (blockIdx.x == 0 && t == 0) row_ptr[n] = E;
}

__global__ __launch_bounds__(256) void scatter_kernel(
    const int* __restrict__ dst, const int* __restrict__ src,
    const float* __restrict__ eattr, int* __restrict__ cursor,
    int2* __restrict__ epack, int E)
{
    int e = blockIdx.x * 256 + threadIdx.x;
    if (e < E) {
        int pos = atomicAdd(&cursor[dst[e]], 1);
        epack[pos] = make_int2(src[e], __float_as_int(eattr[e]));
    }
}

// ---------------- layer-0 coefficient precompute: 24 constants ----------------
// For head h, k-basis t in {Wk row0, Wk row1, bk, We}:
//   (q_i . K_t)/8 = x0*C[h][t][0] + x1*C[h][t][1] + C[h][t][2]
// with C[..0] = (Wq0.K_t)/8, C[..1] = (Wq1.K_t)/8, C[..2] = (bq.K_t)/8.
__global__ __launch_bounds__(128) void coef0_kernel(
    const float* __restrict__ Wq, const float* __restrict__ bq,
    const float* __restrict__ Wk, const float* __restrict__ bk,
    const float* __restrict__ We, float* __restrict__ coef)
{
    int w = threadIdx.x >> 6, l = threadIdx.x & 63;
    int j = w * 64 + l;
    float q0 = Wq[j], q1 = Wq[HD + j], qb = bq[j];
    float kv[4] = {Wk[j], Wk[HD + j], bk[j], We[j]};
    #pragma unroll
    for (int t = 0; t < 4; ++t) {
        float m0 = wave_reduce(kv[t] * q0);
        float m1 = wave_reduce(kv[t] * q1);
        float m2 = wave_reduce(kv[t] * qb);
        if (l == 0) {
            coef[w * 12 + t * 3 + 0] = m0 * 0.125f;
            coef[w * 12 + t * 3 + 1] = m1 * 0.125f;
            coef[w * 12 + t * 3 + 2] = m2 * 0.125f;
        }
    }
}

// ---------------- layer-0 attention scalars: ONE THREAD PER NODE --------------
// Online softmax over edges, accumulating (s, Sx, Sy, Se) per head:
//   agg_j = Wv0_j*Sx + Wv1_j*Sy + bv_j*s + We_j*Se   (reconstructed in attn0b)
__global__ __launch_bounds__(256) void attn0a_kernel(
    const float* __restrict__ x, const float* __restrict__ coef,
    const int2* __restrict__ epack, const int* __restrict__ row_ptr,
    float4* __restrict__ S, int n)
{
    int i = blockIdx.x * 256 + threadIdx.x;
    if (i >= n) return;
    float C[24];
    #pragma unroll
    for (int t = 0; t < 24; ++t) C[t] = coef[t];   // uniform -> s_loads
    float x0 = x[2 * i], x1 = x[2 * i + 1];
    // per-node per-head logit coefficients
    float c0A = fmaf(x1, C[1],  fmaf(x0, C[0],  C[2]));
    float c1A = fmaf(x1, C[4],  fmaf(x0, C[3],  C[5]));
    float cbA = fmaf(x1, C[7],  fmaf(x0, C[6],  C[8]));
    float cwA = fmaf(x1, C[10], fmaf(x0, C[9],  C[11]));
    float c0B = fmaf(x1, C[13], fmaf(x0, C[12], C[14]));
    float c1B = fmaf(x1, C[16], fmaf(x0, C[15], C[17]));
    float cbB = fmaf(x1, C[19], fmaf(x0, C[18], C[20]));
    float cwB = fmaf(x1, C[22], fmaf(x0, C[21], C[23]));

    int p0 = row_ptr[i], p1 = row_ptr[i + 1];
    float mA = -INFINITY, sA = 0.f, SxA = 0.f, SyA = 0.f, SeA = 0.f;
    float mB = -INFINITY, sB = 0.f, SxB = 0.f, SyB = 0.f, SeB = 0.f;

    int2 epn = (p0 < p1) ? epack[p0] : make_int2(0, 0);
    for (int p = p0; p < p1; ++p) {
        int2 ep = epn;
        if (p + 1 < p1) epn = epack[p + 1];
        float ea = __int_as_float(ep.y);
        float2 xs = *(const float2*)&x[2 * ep.x];
        float lgA = fmaf(ea, cwA, fmaf(xs.y, c1A, fmaf(xs.x, c0A, cbA)));
        float lgB = fmaf(ea, cwB, fmaf(xs.y, c1B, fmaf(xs.x, c0B, cbB)));
        {
            float nm = fmaxf(mA, lgA);
            float sc = __expf(mA - nm);
            float ex = __expf(lgA - nm);
            sA  = fmaf(sA,  sc, ex);
            SxA = fmaf(SxA, sc, ex * xs.x);
            SyA = fmaf(SyA, sc, ex * xs.y);
            SeA = fmaf(SeA, sc, ex * ea);
            mA = nm;
        }
        {
            float nm = fmaxf(mB, lgB);
            float sc = __expf(mB - nm);
            float ex = __expf(lgB - nm);
            sB  = fmaf(sB,  sc, ex);
            SxB = fmaf(SxB, sc, ex * xs.x);
            SyB = fmaf(SyB, sc, ex * xs.y);
            SeB = fmaf(SeB, sc, ex * ea);
            mB = nm;
        }
    }
    S[(size_t)i * 2]     = make_float4(sA, SxA, SyA, SeA);
    S[(size_t)i * 2 + 1] = make_float4(sB, SxB, SyB, SeB);
}

// ---------------- layer-0 output reconstruction (elementwise, coalesced) --------
__global__ __launch_bounds__(256) void attn0b_kernel(
    const float* __restrict__ x, const float4* __restrict__ S,
    const float* __restrict__ Wv, const float* __restrict__ bv,
    const float* __restrict__ We,
    const float* __restrict__ Ws, const float* __restrict__ bs,
    float* __restrict__ out, int n)
{
    int gid = blockIdx.x * 256 + threadIdx.x;
    if (gid >= n * HD) return;
    int i = gid >> 7, j = gid & 127, h = j >> 6;
    float4 Sv = S[(size_t)i * 2 + h];              // (s, Sx, Sy, Se)
    float x0 = x[2 * i], x1 = x[2 * i + 1];
    float num = fmaf(Wv[j], Sv.y, fmaf(Wv[HD + j], Sv.z,
                fmaf(bv[j], Sv.x, We[j] * Sv.w)));
    float sk = fmaf(x1, Ws[HD + j], fmaf(x0, Ws[j], bs[j]));
    out[gid] = fmaxf(num / (Sv.x + 1e-16f) + sk, 0.f);
}

// ---------------- layer-1 attention: fp16 q/s/kv, depth-4 pipeline --------------
__global__ __launch_bounds__(256) void attn_kernel(
    const __half* __restrict__ qh, const __half* __restrict__ kvh,
    const __half* __restrict__ sh, const float* __restrict__ We,
    const int2* __restrict__ epack, const int* __restrict__ row_ptr,
    float* __restrict__ out, int n)
{
    int i = blockIdx.x * 4 + (threadIdx.x >> 6);
    if (i >= n) return;
    int l = threadIdx.x & 63;
    const int2* kv8 = (const int2*)kvh;   // 8B = (k2l,k2l+1,v2l,v2l+1) fp16
    const __half2* qh2 = (const __half2*)qh;
    const __half2* sh2 = (const __half2*)sh;
    float2 q  = __half22float2(qh2[(size_t)i * 64 + l]);
    float2 we = *(const float2*)&We[2 * l];
    int p0 = __builtin_amdgcn_readfirstlane(row_ptr[i]);
    int p1 = __builtin_amdgcn_readfirstlane(row_ptr[i + 1]);

    float m = -INFINITY, s = 0.f;
    float2 acc = make_float2(0.f, 0.f);

    int2 kv0 = {}, kv1 = {}, kv2 = {}, kv3 = {};
    float ea0 = 0.f, ea1 = 0.f, ea2 = 0.f, ea3 = 0.f;

#define LD1(t, idx) do { if ((idx) < p1) { int2 ep_ = epack[idx]; \
    ea##t = __int_as_float(ep_.y); kv##t = kv8[(size_t)ep_.x * 64 + l]; } } while (0)

#define KVX(raw, ea, kx, ky, vx, vy) \
    float2 kf_##kx = __half22float2(*(const __half2*)&raw.x); \
    float2 vf_##kx = __half22float2(*(const __half2*)&raw.y); \
    float kx = fmaf(ea, we.x, kf_##kx.x), ky = fmaf(ea, we.y, kf_##kx.y); \
    float vx = fmaf(ea, we.x, vf_##kx.x), vy = fmaf(ea, we.y, vf_##kx.y);

    LD1(0, p0); LD1(1, p0 + 1); LD1(2, p0 + 2); LD1(3, p0 + 3);

    int p = p0;
    for (; p + 3 < p1; p += 4) {
        int2 c0 = kv0, c1 = kv1, c2 = kv2, c3 = kv3;
        float a0 = ea0, a1 = ea1, a2 = ea2, a3 = ea3;
        LD1(0, p + 4); LD1(1, p + 5); LD1(2, p + 6); LD1(3, p + 7);
        {
            KVX(c0, a0, kAx, kAy, vAx, vAy)
            KVX(c1, a1, kBx, kBy, vBx, vBy)
            float lA = half_reduce(fmaf(q.x, kAx, q.y * kAy)) * 0.125f;
            float lB = half_reduce(fmaf(q.x, kBx, q.y * kBy)) * 0.125f;
            pair_update_s(m, s, acc, lA, lB, vAx, vAy, vBx, vBy);
        }
        {
            KVX(c2, a2, kAx, kAy, vAx, vAy)
            KVX(c3, a3, kBx, kBy, vBx, vBy)
            float lA = half_reduce(fmaf(q.x, kAx, q.y * kAy)) * 0.125f;
            float lB = half_reduce(fmaf(q.x, kBx, q.y * kBy)) * 0.125f;
            pair_update_s(m, s, acc, lA, lB, vAx, vAy, vBx, vBy);
        }
    }
    int rem = p1 - p;
    if (rem >= 2) {
        KVX(kv0, ea0, kAx, kAy, vAx, vAy)
        KVX(kv1, ea1, kBx, kBy, vBx, vBy)
        float lA = half_reduce(fmaf(q.x, kAx, q.y * kAy)) * 0.125f;
        float lB = half_reduce(fmaf(q.x, kBx, q.y * kBy)) * 0.125f;
        pair_update_s(m, s, acc, lA, lB, vAx, vAy, vBx, vBy);
    }
    if (rem == 1) {
        KVX(kv0, ea0, kx, ky, vx, vy)
        single_update_s(m, s, acc, half_reduce(fmaf(q.x, kx, q.y * ky)) * 0.125f, vx, vy);
    } else if (rem == 3) {
        KVX(kv2, ea2, kx, ky, vx, vy)
        single_update_s(m, s, acc, half_reduce(fmaf(q.x, kx, q.y * ky)) * 0.125f, vx, vy);
    }

    float inv = 1.f / (s + 1e-16f);
    float2 skp = __half22float2(sh2[(size_t)i * 64 + l]);
    float2 res;
    res.x = fmaxf(fmaf(acc.x, inv, skp.x), 0.f);
    res.y = fmaxf(fmaf(acc.y, inv, skp.y), 0.f);
    *(float2*)&out[(size_t)i * HD + 2 * l] = res;
}

// ---------------- W pre-pack: f32 [128,128]x4 -> mfma B-fragment order, bf16 hi/lo ----
__global__ __launch_bounds__(256) void pack_kernel(
    const float* __restrict__ Wq, const float* __restrict__ Wk,
    const float* __restrict__ Wv, const float* __restrict__ Ws,
    const float* __restrict__ bq, const float* __restrict__ bk,
    const float* __restrict__ bv, const float* __restrict__ bs,
    unsigned short* __restrict__ Wph, unsigned short* __restrict__ Wpl,
    float* __restrict__ bias_cat)
{
    int id = blockIdx.x * 256 + threadIdx.x;   // 65536 fragment entries
    if (id < 65536) {
        int j = id & 7, lane = (id >> 3) & 63, ks = (id >> 9) & 3, gnt = id >> 11;
        int k = ks * 32 + (lane >> 4) * 8 + j;
        int ncol = gnt * 16 + (lane & 15);
        int mat = ncol >> 7, d = ncol & 127;
        const float* W = (mat == 0) ? Wq : (mat == 1) ? Wk : (mat == 2) ? Wv : Ws;
        float w = W[k * HD + d];
        unsigned short hi = f2bf(w);
        Wph[id] = hi;
        Wpl[id] = f2bf(w - bf2f(hi));
    }
    if (id < 512) {
        int mat = id >> 7, d = id & 127;
        const float* b = (mat == 0) ? bq : (mat == 1) ? bk : (mat == 2) ? bv : bs;
        bias_cat[id] = b[d];
    }
}

// ---------------- layer-1 linears: split-bf16 MFMA, 128 rows/block --------------
// blockIdx.y = 0 -> mats q,s (gnt 0..7, 24..31): direct half2 stores
// blockIdx.y = 1 -> mats k,v (gnt 8..23): LDS-staged kv tile, coalesced f4 flush
__global__ __launch_bounds__(256) void lin1_mfma(
    const float* __restrict__ A,
    const unsigned short* __restrict__ Wph, const unsigned short* __restrict__ Wpl,
    const float* __restrict__ bias_cat,
    __half* __restrict__ qh, __half* __restrict__ kvh, __half* __restrict__ sh,
    int n)
{
    __shared__ float As[128 * 128];   // 64 KB, XOR-swizzled; reused as kv out-stage (y==1)
    int tid = threadIdx.x;
    int row0 = blockIdx.x * 128;
    int yb = blockIdx.y;

    #pragma unroll
    for (int it = 0; it < 16; ++it) {
        int idx = (it * 256 + tid) * 4;
        int r = idx >> 7, c = idx & 127;
        float4 av = make_float4(0.f, 0.f, 0.f, 0.f);
        if (row0 + r < n) av = *(const float4*)&A[(size_t)(row0 + r) * HD + c];
        int sl = (c >> 2) ^ (r & 7);
        *(float4*)&As[r * 128 + sl * 4] = av;
    }
    __syncthreads();

    int wave = tid >> 6, lane = tid & 63;
    int m = lane & 15, quad = lane >> 4;

    bf16x8 ah[2][4], al[2][4];
    #pragma unroll
    for (int sub = 0; sub < 2; ++sub) {
        int r = wave * 32 + sub * 16 + m;
        const float* base = &As[r * 128];
        int sw = r & 7;
        #pragma unroll
        for (int ks = 0; ks < 4; ++ks) {
            int i40 = (ks * 8 + quad * 2) ^ sw;
            int i41 = (ks * 8 + quad * 2 + 1) ^ sw;
            float4 x0 = *(const float4*)&base[i40 * 4];
            float4 x1 = *(const float4*)&base[i41 * 4];
            float v[8] = {x0.x, x0.y, x0.z, x0.w, x1.x, x1.y, x1.z, x1.w};
            #pragma unroll
            for (int j = 0; j < 8; ++j) {
                unsigned short hi = f2bf(v[j]);
                ah[sub][ks][j] = (short)hi;
                al[sub][ks][j] = (short)f2bf(v[j] - bf2f(hi));
            }
        }
    }
    __syncthreads();   // As now dead -> reusable as kv out-stage

    const bf16x8* PH = (const bf16x8*)Wph;
    const bf16x8* PL = (const bf16x8*)Wpl;
    __half2* qh2 = (__half2*)qh;
    __half2* sh2 = (__half2*)sh;
    __half*  kvS = (__half*)As;

    #define GNT_OF(nt) ((yb == 0) ? (((nt) < 8) ? (nt) : (nt) + 16) : (nt) + 8)

    bf16x8 bhA[4], blA[4], bhB[4], blB[4];
    {
        int g0 = GNT_OF(0);
        #pragma unroll
        for (int ks = 0; ks < 4; ++ks) {
            bhA[ks] = PH[(g0 * 4 + ks) * 64 + lane];
            blA[ks] = PL[(g0 * 4 + ks) * 64 + lane];
        }
    }

    for (int nt = 0; nt < 16; ++nt) {
        int gnt = GNT_OF(nt);
        if (nt + 1 < 16) {
            int g2 = GNT_OF(nt + 1);
            #pragma unroll
            for (int ks = 0; ks < 4; ++ks) {
                bhB[ks] = PH[(g2 * 4 + ks) * 64 + lane];
                blB[ks] = PL[(g2 * 4 + ks) * 64 + lane];
            }
        }
        f32x4 acc0 = {0.f, 0.f, 0.f, 0.f};
        f32x4 acc1 = {0.f, 0.f, 0.f, 0.f};
        #pragma unroll
        for (int ks = 0; ks < 4; ++ks) {
            acc0 = __builtin_amdgcn_mfma_f32_16x16x32_bf16(ah[0][ks], bhA[ks], acc0, 0, 0, 0);
            acc1 = __builtin_amdgcn_mfma_f32_16x16x32_bf16(ah[1][ks], bhA[ks], acc1, 0, 0, 0);
            acc0 = __builtin_amdgcn_mfma_f32_16x16x32_bf16(ah[0][ks], blA[ks], acc0, 0, 0, 0);
            acc1 = __builtin_amdgcn_mfma_f32_16x16x32_bf16(ah[1][ks], blA[ks], acc1, 0, 0, 0);
            acc0 = __builtin_amdgcn_mfma_f32_16x16x32_bf16(al[0][ks], bhA[ks], acc0, 0, 0, 0);
            acc1 = __builtin_amdgcn_mfma_f32_16x16x32_bf16(al[1][ks], bhA[ks], acc1, 0, 0, 0);
        }
        int ocol = gnt * 16 + m;
        int d = ocol & 127;
        float bias = bias_cat[ocol];
        if (yb == 0) {
            __half2* dst = (gnt < 8) ? qh2 : sh2;
            bool evenl = (m & 1) == 0;
            #pragma unroll
            for (int sub = 0; sub < 2; ++sub) {
                f32x4 acc = sub ? acc1 : acc0;
                #pragma unroll
                for (int reg = 0; reg < 4; ++reg) {
                    int orow = row0 + wave * 32 + sub * 16 + quad * 4 + reg;
                    float val = acc[reg] + bias;
                    float other = __shfl_xor(val, 1, 64);
                    if (orow < n && evenl)
                        dst[(size_t)orow * 64 + (d >> 1)] = __floats2half2_rn(val, other);
                }
            }
        } else {
            int slot = 4 * (d >> 1) + (d & 1) + ((gnt >= 16) ? 2 : 0);
            #pragma unroll
            for (int sub = 0; sub < 2; ++sub) {
                f32x4 acc = sub ? acc1 : acc0;
                #pragma unroll
                for (int reg = 0; reg < 4; ++reg) {
                    int row_l = wave * 32 + sub * 16 + quad * 4 + reg;
                    kvS[row_l * 256 + slot] = __float2half(acc[reg] + bias);
                }
            }
        }
        #pragma unroll
        for (int ks = 0; ks < 4; ++ks) { bhA[ks] = bhB[ks]; blA[ks] = blB[ks]; }
    }

    if (yb == 1) {
        __syncthreads();
        const float4* kvS4 = (const float4*)kvS;
        float4* kvh4 = (float4*)kvh;
        #pragma unroll
        for (int it = 0; it < 16; ++it) {
            int idx = it * 256 + tid;
            int row = idx >> 5, c4 = idx & 31;
            if (row0 + row < n)
                kvh4[(size_t)(row0 + row) * 32 + c4] = kvS4[row * 32 + c4];
        }
    }
    #undef GNT_OF
}

// ---------------- mean-pool (batch sorted -> run-length partials) ----------------
__global__ __launch_bounds__(128) void pool_kernel(
    const float* __restrict__ h, const int* __restrict__ batch,
    float* __restrict__ gsums, float* __restrict__ gcnt, int n)
{
    __shared__ int sb[64];
    int i0 = blockIdx.x * 64;
    int d = threadIdx.x;
    int iend = i0 + 64; if (iend > n) iend = n;
    int csize = iend - i0;
    if (d < csize) sb[d] = batch[i0 + d];
    __syncthreads();
    if (csize <= 0) return;
    float local = 0.f;
    int cur = sb[0];
    int runc = 0;
    for (int i = i0; i < iend; ++i) {
        int g = sb[i - i0];
        if (g != cur) {
            atomicAdd(&gsums[(size_t)cur * HD + d], local);
            if (d == 0) atomicAdd(&gcnt[cur], (float)runc);
            local = 0.f; runc = 0; cur = g;
        }
        local += h[(size_t)i * HD + d];
        runc++;
    }
    atomicAdd(&gsums[(size_t)cur * HD + d], local);
    if (d == 0) atomicAdd(&gcnt[cur], (float)runc);
}

// ---------------- classifier head: one block per graph ----------------
__global__ __launch_bounds__(128) void cls_kernel(
    const float* __restrict__ gsums, const float* __restrict__ gcnt,
    const float* __restrict__ cW1, const float* __restrict__ cb1,
    const float* __restrict__ cW2, const float* __restrict__ cb2,
    float* __restrict__ out)
{
    __shared__ float g[128];
    __shared__ float t[128];
    int gi = blockIdx.x, j = threadIdx.x;
    float c = fmaxf(gcnt[gi], 1.0f);
    g[j] = gsums[(size_t)gi * HD + j] / c;
    __syncthreads();
    float a = cb1[j];
    for (int k = 0; k < 128; ++k) a = fmaf(g[k], cW1[k * 128 + j], a);
    t[j] = fmaxf(a, 0.f);
    __syncthreads();
    if (j < 30) {
        float a2 = cb2[j];
        for (int k = 0; k < 128; ++k) a2 = fmaf(t[k], cW2[k * 30 + j], a2);
        out[gi * 30 + j] = a2;
    }
}

extern "C" void kernel_launch(void* const* d_in, const int* in_sizes, int n_in,
                              void* d_out, int out_size, void* d_ws, size_t ws_size,
                              hipStream_t stream)
{
    const float* x     = (const float*)d_in[0];
    const int*   ei    = (const int*)d_in[1];
    const float* eattr = (const float*)d_in[2];
    const int*   batch = (const int*)d_in[3];
    const float* l0_Wq = (const float*)d_in[4];
    const float* l0_bq = (const float*)d_in[5];
    const float* l0_Wk = (const float*)d_in[6];
    const float* l0_bk = (const float*)d_in[7];
    const float* l0_Wv = (const float*)d_in[8];
    const float* l0_bv = (const float*)d_in[9];
    const float* l0_We = (const float*)d_in[10];
    const float* l0_Ws = (const float*)d_in[11];
    const float* l0_bs = (const float*)d_in[12];
    const float* l1_Wq = (const float*)d_in[13];
    const float* l1_bq = (const float*)d_in[14];
    const float* l1_Wk = (const float*)d_in[15];
    const float* l1_bk = (const float*)d_in[16];
    const float* l1_Wv = (const float*)d_in[17];
    const float* l1_bv = (const float*)d_in[18];
    const float* l1_We = (const float*)d_in[19];
    const float* l1_Ws = (const float*)d_in[20];
    const float* l1_bs = (const float*)d_in[21];
    const float* cW1   = (const float*)d_in[22];
    const float* cb1   = (const float*)d_in[23];
    const float* cW2   = (const float*)d_in[24];
    const float* cb2   = (const float*)d_in[25];

    int n = in_sizes[0] / 2;     // 50000
    int E = in_sizes[2];         // 800000
    int G = out_size / 30;       // 64
    int B = (n + 511) / 512;     // scan blocks (98)

    size_t nd = (size_t)n * HD;
    float* h      = (float*)d_ws;                 // n*128 f32
    __half* qh    = (__half*)(h + nd);            // n*128 fp16
    __half* sh    = qh + nd;                      // n*128 fp16
    __half* kvh   = sh + nd;                      // n*256 fp16 (interleaved kv pairs)
    float* bias_cat = (float*)(kvh + (size_t)n * 256);         // 512
    unsigned short* Wph = (unsigned short*)(bias_cat + 512);   // 65536
    unsigned short* Wpl = Wph + 65536;                         // 65536
    float* coef   = (float*)(Wpl + 65536);        // 24 (+pad to 8-align: 24 f32 ok)
    float4* S0    = (float4*)(coef + 32);         // n*2 float4 (16B-aligned: offset mult of 16B? coef+32 floats = 128B ✓)
    int2* epack   = (int2*)(S0 + (size_t)n * 2);  // E
    int* cnt      = (int*)(epack + E);            // n
    int* row_ptr  = cnt + n;                      // n+1 (+1 pad)
    int* cursor   = row_ptr + n + 2;              // n
    int* bsum     = cursor + n;                   // B
    int* boff     = bsum + 256;                   // B
    float* gsums  = (float*)(boff + 256);         // G*128
    float* gcnt   = gsums + (size_t)G * HD;       // G

    const int* srcI = ei;
    const int* dstI = ei + E;

    hipMemsetAsync(cnt, 0, (size_t)n * sizeof(int), stream);
    hipMemsetAsync(gsums, 0, ((size_t)G * HD + G) * sizeof(float), stream);

    hist_kernel<<<(E + 255) / 256, 256, 0, stream>>>(dstI, cnt, E);
    scanA_kernel<<<B, 256, 0, stream>>>(cnt, row_ptr, bsum, n);
    scanB_kernel<<<1, 256, 0, stream>>>(bsum, boff, B);
    scanC_kernel<<<B, 256, 0, stream>>>(row_ptr, cursor, boff, n, E);
    scatter_kernel<<<(E + 255) / 256, 256, 0, stream>>>(dstI, srcI, eattr, cursor, epack, E);

    pack_kernel<<<256, 256, 0, stream>>>(l1_Wq, l1_Wk, l1_Wv, l1_Ws,
                                         l1_bq, l1_bk, l1_bv, l1_bs,
                                         Wph, Wpl, bias_cat);
    coef0_kernel<<<1, 128, 0, stream>>>(l0_Wq, l0_bq, l0_Wk, l0_bk, l0_We, coef);

    attn0a_kernel<<<(n + 255) / 256, 256, 0, stream>>>(
        x, coef, epack, row_ptr, S0, n);
    attn0b_kernel<<<(n * HD + 255) / 256, 256, 0, stream>>>(
        x, S0, l0_Wv, l0_bv, l0_We, l0_Ws, l0_bs, h, n);

    lin1_mfma<<<dim3((n + 127) / 128, 2), 256, 0, stream>>>(
        h, Wph, Wpl, bias_cat, qh, kvh, sh, n);
    attn_kernel<<<(n + 3) / 4, 256, 0, stream>>>(
        qh, kvh, sh, l1_We, epack, row_ptr, h, n);

    pool_kernel<<<(n + 63) / 64, 128, 0, stream>>>(h, batch, gsums, gcnt, n);
    cls_kernel<<<G, 128, 0, stream>>>(gsums, gcnt, cW1, cb1, cW2, cb2, (float*)d_out);
}

// Round 11
// 355.870 us; speedup vs baseline: 1.1632x; 1.0516x over previous
//
#include <hip/hip_runtime.h>
#include <hip/hip_fp16.h>
#include <cstdint>
#include <cstddef>

#define HD 128

typedef short bf16x8 __attribute__((ext_vector_type(8)));   // 8 bf16 in 4 VGPRs
typedef float f32x4 __attribute__((ext_vector_type(4)));

__device__ __forceinline__ unsigned short f2bf(float f) {
    unsigned int u = __float_as_uint(f);
    u += 0x7fff + ((u >> 16) & 1);          // round-to-nearest-even
    return (unsigned short)(u >> 16);
}
__device__ __forceinline__ float bf2f(unsigned short h) {
    return __uint_as_float(((unsigned int)h) << 16);
}

// DPP butterfly add (VALU pipe) — reduce within each 32-lane half (per head)
template<int CTRL>
__device__ __forceinline__ float dpp_add(float x) {
    int y = __builtin_amdgcn_update_dpp(0, __float_as_int(x), CTRL, 0xF, 0xF, true);
    return x + __int_as_float(y);
}
__device__ __forceinline__ float half_reduce(float x) {
    x = dpp_add<0xB1>(x);    // quad_perm xor1
    x = dpp_add<0x4E>(x);    // quad_perm xor2
    x = dpp_add<0x124>(x);   // row_ror:4
    x = dpp_add<0x128>(x);   // row_ror:8 -> row(16) sums
    x += __shfl_xor(x, 16, 64);  // combine two rows of the 32-half
    return x;
}
__device__ __forceinline__ float wave_reduce(float x) {
    x = half_reduce(x);
    x += __shfl_xor(x, 32, 64);
    return x;
}

// fused dual online-softmax update, logits precomputed
__device__ __forceinline__ void pair_update_s(
    float& m, float& s, float2& acc,
    float lA, float lB,
    float vAx, float vAy, float vBx, float vBy)
{
    float nm = fmaxf(fmaxf(m, lA), lB);
    float sc = __expf(m - nm);
    float eA = __expf(lA - nm);
    float eB = __expf(lB - nm);
    s     = fmaf(s, sc, eA + eB);
    acc.x = fmaf(acc.x, sc, fmaf(eA, vAx, eB * vBx));
    acc.y = fmaf(acc.y, sc, fmaf(eA, vAy, eB * vBy));
    m = nm;
}
__device__ __forceinline__ void single_update_s(
    float& m, float& s, float2& acc,
    float lg, float vx, float vy)
{
    float nm = fmaxf(m, lg);
    float sc = __expf(m - nm);
    float ex = __expf(lg - nm);
    s     = fmaf(s, sc, ex);
    acc.x = fmaf(acc.x, sc, ex * vx);
    acc.y = fmaf(acc.y, sc, ex * vy);
    m = nm;
}

// ---------------- CSR-by-dst build ----------------
__global__ __launch_bounds__(256) void hist_kernel(
    const int* __restrict__ dst, int* __restrict__ cnt, int E)
{
    int e = blockIdx.x * 256 + threadIdx.x;
    if (e < E) atomicAdd(&cnt[dst[e]], 1);
}

// 3-phase hierarchical exclusive scan (512 elems/block in LDS)
__global__ __launch_bounds__(256) void scanA_kernel(
    const int* __restrict__ cnt, int* __restrict__ row_ptr,
    int* __restrict__ bsum, int n)
{
    __shared__ int sdata[256];
    int t = threadIdx.x;
    int base = blockIdx.x * 512 + 2 * t;
    int a = (base < n) ? cnt[base] : 0;
    int b = (base + 1 < n) ? cnt[base + 1] : 0;
    int local = a + b;
    sdata[t] = local;
    __syncthreads();
    #pragma unroll
    for (int off = 1; off < 256; off <<= 1) {
        int val = (t >= off) ? sdata[t - off] : 0;
        __syncthreads();
        sdata[t] += val;
        __syncthreads();
    }
    int excl = sdata[t] - local;
    if (base < n)     row_ptr[base] = excl;
    if (base + 1 < n) row_ptr[base + 1] = excl + a;
    if (t == 255) bsum[blockIdx.x] = sdata[255];
}

__global__ __launch_bounds__(256) void scanB_kernel(
    const int* __restrict__ bsum, int* __restrict__ boff, int B)
{
    __shared__ int sdata[256];
    int t = threadIdx.x;
    int local = (t < B) ? bsum[t] : 0;
    sdata[t] = local;
    __syncthreads();
    #pragma unroll
    for (int off = 1; off < 256; off <<= 1) {
        int val = (t >= off) ? sdata[t - off] : 0;
        __syncthreads();
        sdata[t] += val;
        __syncthreads();
    }
    if (t < B) boff[t] = sdata[t] - local;
}

__global__ __launch_bounds__(256) void scanC_kernel(
    int* __restrict__ row_ptr, int* __restrict__ cursor,
    const int* __restrict__ boff, int n, int E)
{
    int t = threadIdx.x;
    int base = blockIdx.x * 512 + 2 * t;
    int off = boff[blockIdx.x];
    if (base + 1 < n) {
        int2 v = *(int2*)&row_ptr[base];
        v.x += off; v.y += off;
        *(int2*)&row_ptr[base] = v;
        *(int2*)&cursor[base]  = v;
    } else if (base < n) {
        int v = row_ptr[base] + off;
        row_ptr[base] = v; cursor[base] = v;
    }
    if (blockIdx.x == 0 && t == 0) row_ptr[n] = E;
}

__global__ __launch_bounds__(256) void scatter_kernel(
    const int* __restrict__ dst, const int* __restrict__ src,
    const float* __restrict__ eattr, int* __restrict__ cursor,
    int2* __restrict__ epack, int E)
{
    int e = blockIdx.x * 256 + threadIdx.x;
    if (e < E) {
        int pos = atomicAdd(&cursor[dst[e]], 1);
        epack[pos] = make_int2(src[e], __float_as_int(eattr[e]));
    }
}

// ---------------- layer-0 coefficient precompute: 24 constants ----------------
__global__ __launch_bounds__(128) void coef0_kernel(
    const float* __restrict__ Wq, const float* __restrict__ bq,
    const float* __restrict__ Wk, const float* __restrict__ bk,
    const float* __restrict__ We, float* __restrict__ coef)
{
    int w = threadIdx.x >> 6, l = threadIdx.x & 63;
    int j = w * 64 + l;
    float q0 = Wq[j], q1 = Wq[HD + j], qb = bq[j];
    float kv[4] = {Wk[j], Wk[HD + j], bk[j], We[j]};
    #pragma unroll
    for (int t = 0; t < 4; ++t) {
        float m0 = wave_reduce(kv[t] * q0);
        float m1 = wave_reduce(kv[t] * q1);
        float m2 = wave_reduce(kv[t] * qb);
        if (l == 0) {
            coef[w * 12 + t * 3 + 0] = m0 * 0.125f;
            coef[w * 12 + t * 3 + 1] = m1 * 0.125f;
            coef[w * 12 + t * 3 + 2] = m2 * 0.125f;
        }
    }
}

// ---------------- layer-0 attention scalars: ONE THREAD PER NODE --------------
__global__ __launch_bounds__(256) void attn0a_kernel(
    const float* __restrict__ x, const float* __restrict__ coef,
    const int2* __restrict__ epack, const int* __restrict__ row_ptr,
    float4* __restrict__ S, int n)
{
    int i = blockIdx.x * 256 + threadIdx.x;
    if (i >= n) return;
    float C[24];
    #pragma unroll
    for (int t = 0; t < 24; ++t) C[t] = coef[t];   // uniform -> s_loads
    float x0 = x[2 * i], x1 = x[2 * i + 1];
    float c0A = fmaf(x1, C[1],  fmaf(x0, C[0],  C[2]));
    float c1A = fmaf(x1, C[4],  fmaf(x0, C[3],  C[5]));
    float cbA = fmaf(x1, C[7],  fmaf(x0, C[6],  C[8]));
    float cwA = fmaf(x1, C[10], fmaf(x0, C[9],  C[11]));
    float c0B = fmaf(x1, C[13], fmaf(x0, C[12], C[14]));
    float c1B = fmaf(x1, C[16], fmaf(x0, C[15], C[17]));
    float cbB = fmaf(x1, C[19], fmaf(x0, C[18], C[20]));
    float cwB = fmaf(x1, C[22], fmaf(x0, C[21], C[23]));

    int p0 = row_ptr[i], p1 = row_ptr[i + 1];
    float mA = -INFINITY, sA = 0.f, SxA = 0.f, SyA = 0.f, SeA = 0.f;
    float mB = -INFINITY, sB = 0.f, SxB = 0.f, SyB = 0.f, SeB = 0.f;

    int2 epn = (p0 < p1) ? epack[p0] : make_int2(0, 0);
    for (int p = p0; p < p1; ++p) {
        int2 ep = epn;
        if (p + 1 < p1) epn = epack[p + 1];
        float ea = __int_as_float(ep.y);
        float2 xs = *(const float2*)&x[2 * ep.x];
        float lgA = fmaf(ea, cwA, fmaf(xs.y, c1A, fmaf(xs.x, c0A, cbA)));
        float lgB = fmaf(ea, cwB, fmaf(xs.y, c1B, fmaf(xs.x, c0B, cbB)));
        {
            float nm = fmaxf(mA, lgA);
            float sc = __expf(mA - nm);
            float ex = __expf(lgA - nm);
            sA  = fmaf(sA,  sc, ex);
            SxA = fmaf(SxA, sc, ex * xs.x);
            SyA = fmaf(SyA, sc, ex * xs.y);
            SeA = fmaf(SeA, sc, ex * ea);
            mA = nm;
        }
        {
            float nm = fmaxf(mB, lgB);
            float sc = __expf(mB - nm);
            float ex = __expf(lgB - nm);
            sB  = fmaf(sB,  sc, ex);
            SxB = fmaf(SxB, sc, ex * xs.x);
            SyB = fmaf(SyB, sc, ex * xs.y);
            SeB = fmaf(SeB, sc, ex * ea);
            mB = nm;
        }
    }
    S[(size_t)i * 2]     = make_float4(sA, SxA, SyA, SeA);
    S[(size_t)i * 2 + 1] = make_float4(sB, SxB, SyB, SeB);
}

// ---------------- layer-1 attention: fp16 q/s/kv, depth-4 pipeline; fp16 out ----
__global__ __launch_bounds__(256) void attn_kernel(
    const __half* __restrict__ qh, const __half* __restrict__ kvh,
    const __half* __restrict__ sh, const float* __restrict__ We,
    const int2* __restrict__ epack, const int* __restrict__ row_ptr,
    __half2* __restrict__ outh, int n)
{
    int i = blockIdx.x * 4 + (threadIdx.x >> 6);
    if (i >= n) return;
    int l = threadIdx.x & 63;
    const int2* kv8 = (const int2*)kvh;   // 8B = (k2l,k2l+1,v2l,v2l+1) fp16
    const __half2* qh2 = (const __half2*)qh;
    const __half2* sh2 = (const __half2*)sh;
    float2 q  = __half22float2(qh2[(size_t)i * 64 + l]);
    float2 we = *(const float2*)&We[2 * l];
    int p0 = __builtin_amdgcn_readfirstlane(row_ptr[i]);
    int p1 = __builtin_amdgcn_readfirstlane(row_ptr[i + 1]);

    float m = -INFINITY, s = 0.f;
    float2 acc = make_float2(0.f, 0.f);

    int2 kv0 = {}, kv1 = {}, kv2 = {}, kv3 = {};
    float ea0 = 0.f, ea1 = 0.f, ea2 = 0.f, ea3 = 0.f;

#define LD1(t, idx) do { if ((idx) < p1) { int2 ep_ = epack[idx]; \
    ea##t = __int_as_float(ep_.y); kv##t = kv8[(size_t)ep_.x * 64 + l]; } } while (0)

#define KVX(raw, ea, kx, ky, vx, vy) \
    float2 kf_##kx = __half22float2(*(const __half2*)&raw.x); \
    float2 vf_##kx = __half22float2(*(const __half2*)&raw.y); \
    float kx = fmaf(ea, we.x, kf_##kx.x), ky = fmaf(ea, we.y, kf_##kx.y); \
    float vx = fmaf(ea, we.x, vf_##kx.x), vy = fmaf(ea, we.y, vf_##kx.y);

    LD1(0, p0); LD1(1, p0 + 1); LD1(2, p0 + 2); LD1(3, p0 + 3);

    int p = p0;
    for (; p + 3 < p1; p += 4) {
        int2 c0 = kv0, c1 = kv1, c2 = kv2, c3 = kv3;
        float a0 = ea0, a1 = ea1, a2 = ea2, a3 = ea3;
        LD1(0, p + 4); LD1(1, p + 5); LD1(2, p + 6); LD1(3, p + 7);
        {
            KVX(c0, a0, kAx, kAy, vAx, vAy)
            KVX(c1, a1, kBx, kBy, vBx, vBy)
            float lA = half_reduce(fmaf(q.x, kAx, q.y * kAy)) * 0.125f;
            float lB = half_reduce(fmaf(q.x, kBx, q.y * kBy)) * 0.125f;
            pair_update_s(m, s, acc, lA, lB, vAx, vAy, vBx, vBy);
        }
        {
            KVX(c2, a2, kAx, kAy, vAx, vAy)
            KVX(c3, a3, kBx, kBy, vBx, vBy)
            float lA = half_reduce(fmaf(q.x, kAx, q.y * kAy)) * 0.125f;
            float lB = half_reduce(fmaf(q.x, kBx, q.y * kBy)) * 0.125f;
            pair_update_s(m, s, acc, lA, lB, vAx, vAy, vBx, vBy);
        }
    }
    int rem = p1 - p;
    if (rem >= 2) {
        KVX(kv0, ea0, kAx, kAy, vAx, vAy)
        KVX(kv1, ea1, kBx, kBy, vBx, vBy)
        float lA = half_reduce(fmaf(q.x, kAx, q.y * kAy)) * 0.125f;
        float lB = half_reduce(fmaf(q.x, kBx, q.y * kBy)) * 0.125f;
        pair_update_s(m, s, acc, lA, lB, vAx, vAy, vBx, vBy);
    }
    if (rem == 1) {
        KVX(kv0, ea0, kx, ky, vx, vy)
        single_update_s(m, s, acc, half_reduce(fmaf(q.x, kx, q.y * ky)) * 0.125f, vx, vy);
    } else if (rem == 3) {
        KVX(kv2, ea2, kx, ky, vx, vy)
        single_update_s(m, s, acc, half_reduce(fmaf(q.x, kx, q.y * ky)) * 0.125f, vx, vy);
    }

    float inv = 1.f / (s + 1e-16f);
    float2 skp = __half22float2(sh2[(size_t)i * 64 + l]);
    float rx = fmaxf(fmaf(acc.x, inv, skp.x), 0.f);
    float ry = fmaxf(fmaf(acc.y, inv, skp.y), 0.f);
    outh[(size_t)i * 64 + l] = __floats2half2_rn(rx, ry);
}

// ---------------- W pre-pack: f32 [128,128]x4 -> mfma B-fragment order, bf16 hi/lo ----
__global__ __launch_bounds__(256) void pack_kernel(
    const float* __restrict__ Wq, const float* __restrict__ Wk,
    const float* __restrict__ Wv, const float* __restrict__ Ws,
    const float* __restrict__ bq, const float* __restrict__ bk,
    const float* __restrict__ bv, const float* __restrict__ bs,
    unsigned short* __restrict__ Wph, unsigned short* __restrict__ Wpl,
    float* __restrict__ bias_cat)
{
    int id = blockIdx.x * 256 + threadIdx.x;   // 65536 fragment entries
    if (id < 65536) {
        int j = id & 7, lane = (id >> 3) & 63, ks = (id >> 9) & 3, gnt = id >> 11;
        int k = ks * 32 + (lane >> 4) * 8 + j;
        int ncol = gnt * 16 + (lane & 15);
        int mat = ncol >> 7, d = ncol & 127;
        const float* W = (mat == 0) ? Wq : (mat == 1) ? Wk : (mat == 2) ? Wv : Ws;
        float w = W[k * HD + d];
        unsigned short hi = f2bf(w);
        Wph[id] = hi;
        Wpl[id] = f2bf(w - bf2f(hi));
    }
    if (id < 512) {
        int mat = id >> 7, d = id & 127;
        const float* b = (mat == 0) ? bq : (mat == 1) ? bk : (mat == 2) ? bv : bs;
        bias_cat[id] = b[d];
    }
}

// ---------------- layer-1 linears, FUSED layer-0 reconstruction + MFMA ----------
// A-stage computes h0[r,c] = relu((Wv0_c*Sx + Wv1_c*Sy + bv_c*s + We_c*Se)/s + skip)
// on the fly from S0/x (h0 never materialized). Thread owns 4 fixed columns.
// blockIdx.y = 0 -> q,s (direct half2 stores); y = 1 -> k,v (LDS-staged flush)
__global__ __launch_bounds__(256) void lin1_mfma(
    const float* __restrict__ x, const float4* __restrict__ S0,
    const float* __restrict__ l0Wv, const float* __restrict__ l0bv,
    const float* __restrict__ l0We,
    const float* __restrict__ l0Ws, const float* __restrict__ l0bs,
    const unsigned short* __restrict__ Wph, const unsigned short* __restrict__ Wpl,
    const float* __restrict__ bias_cat,
    __half* __restrict__ qh, __half* __restrict__ kvh, __half* __restrict__ sh,
    int n)
{
    __shared__ float As[128 * 128];   // 64 KB, XOR-swizzled; reused as kv out-stage (y==1)
    int tid = threadIdx.x;
    int row0 = blockIdx.x * 128;
    int yb = blockIdx.y;

    // fused h0 compute + stage: thread owns columns c0..c0+3, rows rb + 8*it
    {
        int c4 = tid & 31;
        int c0 = c4 * 4;
        int rb = tid >> 5;            // 0..7
        int hh = c4 >> 4;             // head
        float4 wv0 = *(const float4*)&l0Wv[c0];
        float4 wv1 = *(const float4*)&l0Wv[HD + c0];
        float4 bv4 = *(const float4*)&l0bv[c0];
        float4 we4 = *(const float4*)&l0We[c0];
        float4 ws0 = *(const float4*)&l0Ws[c0];
        float4 ws1 = *(const float4*)&l0Ws[HD + c0];
        float4 bs4 = *(const float4*)&l0bs[c0];
        #pragma unroll
        for (int it = 0; it < 16; ++it) {
            int r = it * 8 + rb;
            float4 av = make_float4(0.f, 0.f, 0.f, 0.f);
            if (row0 + r < n) {
                float2 xr = *(const float2*)&x[2 * (size_t)(row0 + r)];
                float4 Sv = S0[(size_t)(row0 + r) * 2 + hh];
                float inv = 1.f / (Sv.x + 1e-16f);
                float n0 = fmaf(wv0.x, Sv.y, fmaf(wv1.x, Sv.z, fmaf(bv4.x, Sv.x, we4.x * Sv.w)));
                float n1 = fmaf(wv0.y, Sv.y, fmaf(wv1.y, Sv.z, fmaf(bv4.y, Sv.x, we4.y * Sv.w)));
                float n2 = fmaf(wv0.z, Sv.y, fmaf(wv1.z, Sv.z, fmaf(bv4.z, Sv.x, we4.z * Sv.w)));
                float n3 = fmaf(wv0.w, Sv.y, fmaf(wv1.w, Sv.z, fmaf(bv4.w, Sv.x, we4.w * Sv.w)));
                av.x = fmaxf(fmaf(n0, inv, fmaf(xr.y, ws1.x, fmaf(xr.x, ws0.x, bs4.x))), 0.f);
                av.y = fmaxf(fmaf(n1, inv, fmaf(xr.y, ws1.y, fmaf(xr.x, ws0.y, bs4.y))), 0.f);
                av.z = fmaxf(fmaf(n2, inv, fmaf(xr.y, ws1.z, fmaf(xr.x, ws0.z, bs4.z))), 0.f);
                av.w = fmaxf(fmaf(n3, inv, fmaf(xr.y, ws1.w, fmaf(xr.x, ws0.w, bs4.w))), 0.f);
            }
            int sl = c4 ^ (r & 7);
            *(float4*)&As[r * 128 + sl * 4] = av;
        }
    }
    __syncthreads();

    int wave = tid >> 6, lane = tid & 63;
    int m = lane & 15, quad = lane >> 4;

    bf16x8 ah[2][4], al[2][4];
    #pragma unroll
    for (int sub = 0; sub < 2; ++sub) {
        int r = wave * 32 + sub * 16 + m;
        const float* base = &As[r * 128];
        int sw = r & 7;
        #pragma unroll
        for (int ks = 0; ks < 4; ++ks) {
            int i40 = (ks * 8 + quad * 2) ^ sw;
            int i41 = (ks * 8 + quad * 2 + 1) ^ sw;
            float4 x0 = *(const float4*)&base[i40 * 4];
            float4 x1 = *(const float4*)&base[i41 * 4];
            float v[8] = {x0.x, x0.y, x0.z, x0.w, x1.x, x1.y, x1.z, x1.w};
            #pragma unroll
            for (int j = 0; j < 8; ++j) {
                unsigned short hi = f2bf(v[j]);
                ah[sub][ks][j] = (short)hi;
                al[sub][ks][j] = (short)f2bf(v[j] - bf2f(hi));
            }
        }
    }
    __syncthreads();   // As now dead -> reusable as kv out-stage

    const bf16x8* PH = (const bf16x8*)Wph;
    const bf16x8* PL = (const bf16x8*)Wpl;
    __half2* qh2 = (__half2*)qh;
    __half2* sh2 = (__half2*)sh;
    __half*  kvS = (__half*)As;

    #define GNT_OF(nt) ((yb == 0) ? (((nt) < 8) ? (nt) : (nt) + 16) : (nt) + 8)

    bf16x8 bhA[4], blA[4], bhB[4], blB[4];
    {
        int g0 = GNT_OF(0);
        #pragma unroll
        for (int ks = 0; ks < 4; ++ks) {
            bhA[ks] = PH[(g0 * 4 + ks) * 64 + lane];
            blA[ks] = PL[(g0 * 4 + ks) * 64 + lane];
        }
    }

    for (int nt = 0; nt < 16; ++nt) {
        int gnt = GNT_OF(nt);
        if (nt + 1 < 16) {
            int g2 = GNT_OF(nt + 1);
            #pragma unroll
            for (int ks = 0; ks < 4; ++ks) {
                bhB[ks] = PH[(g2 * 4 + ks) * 64 + lane];
                blB[ks] = PL[(g2 * 4 + ks) * 64 + lane];
            }
        }
        f32x4 acc0 = {0.f, 0.f, 0.f, 0.f};
        f32x4 acc1 = {0.f, 0.f, 0.f, 0.f};
        #pragma unroll
        for (int ks = 0; ks < 4; ++ks) {
            acc0 = __builtin_amdgcn_mfma_f32_16x16x32_bf16(ah[0][ks], bhA[ks], acc0, 0, 0, 0);
            acc1 = __builtin_amdgcn_mfma_f32_16x16x32_bf16(ah[1][ks], bhA[ks], acc1, 0, 0, 0);
            acc0 = __builtin_amdgcn_mfma_f32_16x16x32_bf16(ah[0][ks], blA[ks], acc0, 0, 0, 0);
            acc1 = __builtin_amdgcn_mfma_f32_16x16x32_bf16(ah[1][ks], blA[ks], acc1, 0, 0, 0);
            acc0 = __builtin_amdgcn_mfma_f32_16x16x32_bf16(al[0][ks], bhA[ks], acc0, 0, 0, 0);
            acc1 = __builtin_amdgcn_mfma_f32_16x16x32_bf16(al[1][ks], bhA[ks], acc1, 0, 0, 0);
        }
        int ocol = gnt * 16 + m;
        int d = ocol & 127;
        float bias = bias_cat[ocol];
        if (yb == 0) {
            __half2* dst = (gnt < 8) ? qh2 : sh2;
            bool evenl = (m & 1) == 0;
            #pragma unroll
            for (int sub = 0; sub < 2; ++sub) {
                f32x4 acc = sub ? acc1 : acc0;
                #pragma unroll
                for (int reg = 0; reg < 4; ++reg) {
                    int orow = row0 + wave * 32 + sub * 16 + quad * 4 + reg;
                    float val = acc[reg] + bias;
                    float other = __shfl_xor(val, 1, 64);
                    if (orow < n && evenl)
                        dst[(size_t)orow * 64 + (d >> 1)] = __floats2half2_rn(val, other);
                }
            }
        } else {
            int slot = 4 * (d >> 1) + (d & 1) + ((gnt >= 16) ? 2 : 0);
            #pragma unroll
            for (int sub = 0; sub < 2; ++sub) {
                f32x4 acc = sub ? acc1 : acc0;
                #pragma unroll
                for (int reg = 0; reg < 4; ++reg) {
                    int row_l = wave * 32 + sub * 16 + quad * 4 + reg;
                    kvS[row_l * 256 + slot] = __float2half(acc[reg] + bias);
                }
            }
        }
        #pragma unroll
        for (int ks = 0; ks < 4; ++ks) { bhA[ks] = bhB[ks]; blA[ks] = blB[ks]; }
    }

    if (yb == 1) {
        __syncthreads();
        const float4* kvS4 = (const float4*)kvS;
        float4* kvh4 = (float4*)kvh;
        #pragma unroll
        for (int it = 0; it < 16; ++it) {
            int idx = it * 256 + tid;
            int row = idx >> 5, c4 = idx & 31;
            if (row0 + row < n)
                kvh4[(size_t)(row0 + row) * 32 + c4] = kvS4[row * 32 + c4];
        }
    }
    #undef GNT_OF
}

// ---------------- mean-pool (fp16 input; batch sorted -> run-length partials) ----
__global__ __launch_bounds__(128) void pool_kernel(
    const __half* __restrict__ h, const int* __restrict__ batch,
    float* __restrict__ gsums, float* __restrict__ gcnt, int n)
{
    __shared__ int sb[64];
    int i0 = blockIdx.x * 64;
    int d = threadIdx.x;
    int iend = i0 + 64; if (iend > n) iend = n;
    int csize = iend - i0;
    if (d < csize) sb[d] = batch[i0 + d];
    __syncthreads();
    if (csize <= 0) return;
    float local = 0.f;
    int cur = sb[0];
    int runc = 0;
    for (int i = i0; i < iend; ++i) {
        int g = sb[i - i0];
        if (g != cur) {
            atomicAdd(&gsums[(size_t)cur * HD + d], local);
            if (d == 0) atomicAdd(&gcnt[cur], (float)runc);
            local = 0.f; runc = 0; cur = g;
        }
        local += __half2float(h[(size_t)i * HD + d]);
        runc++;
    }
    atomicAdd(&gsums[(size_t)cur * HD + d], local);
    if (d == 0) atomicAdd(&gcnt[cur], (float)runc);
}

// ---------------- classifier head: one block per graph ----------------
__global__ __launch_bounds__(128) void cls_kernel(
    const float* __restrict__ gsums, const float* __restrict__ gcnt,
    const float* __restrict__ cW1, const float* __restrict__ cb1,
    const float* __restrict__ cW2, const float* __restrict__ cb2,
    float* __restrict__ out)
{
    __shared__ float g[128];
    __shared__ float t[128];
    int gi = blockIdx.x, j = threadIdx.x;
    float c = fmaxf(gcnt[gi], 1.0f);
    g[j] = gsums[(size_t)gi * HD + j] / c;
    __syncthreads();
    float a = cb1[j];
    for (int k = 0; k < 128; ++k) a = fmaf(g[k], cW1[k * 128 + j], a);
    t[j] = fmaxf(a, 0.f);
    __syncthreads();
    if (j < 30) {
        float a2 = cb2[j];
        for (int k = 0; k < 128; ++k) a2 = fmaf(t[k], cW2[k * 30 + j], a2);
        out[gi * 30 + j] = a2;
    }
}

extern "C" void kernel_launch(void* const* d_in, const int* in_sizes, int n_in,
                              void* d_out, int out_size, void* d_ws, size_t ws_size,
                              hipStream_t stream)
{
    const float* x     = (const float*)d_in[0];
    const int*   ei    = (const int*)d_in[1];
    const float* eattr = (const float*)d_in[2];
    const int*   batch = (const int*)d_in[3];
    const float* l0_Wq = (const float*)d_in[4];
    const float* l0_bq = (const float*)d_in[5];
    const float* l0_Wk = (const float*)d_in[6];
    const float* l0_bk = (const float*)d_in[7];
    const float* l0_Wv = (const float*)d_in[8];
    const float* l0_bv = (const float*)d_in[9];
    const float* l0_We = (const float*)d_in[10];
    const float* l0_Ws = (const float*)d_in[11];
    const float* l0_bs = (const float*)d_in[12];
    const float* l1_Wq = (const float*)d_in[13];
    const float* l1_bq = (const float*)d_in[14];
    const float* l1_Wk = (const float*)d_in[15];
    const float* l1_bk = (const float*)d_in[16];
    const float* l1_Wv = (const float*)d_in[17];
    const float* l1_bv = (const float*)d_in[18];
    const float* l1_We = (const float*)d_in[19];
    const float* l1_Ws = (const float*)d_in[20];
    const float* l1_bs = (const float*)d_in[21];
    const float* cW1   = (const float*)d_in[22];
    const float* cb1   = (const float*)d_in[23];
    const float* cW2   = (const float*)d_in[24];
    const float* cb2   = (const float*)d_in[25];

    int n = in_sizes[0] / 2;     // 50000
    int E = in_sizes[2];         // 800000
    int G = out_size / 30;       // 64
    int B = (n + 511) / 512;     // scan blocks (98)

    size_t nd = (size_t)n * HD;
    __half* h1    = (__half*)d_ws;                // n*128 fp16 (layer-1 output)
    __half* qh    = h1 + nd;                      // n*128 fp16
    __half* sh    = qh + nd;                      // n*128 fp16
    __half* kvh   = sh + nd;                      // n*256 fp16 (interleaved kv pairs)
    float* bias_cat = (float*)(kvh + (size_t)n * 256);         // 512
    unsigned short* Wph = (unsigned short*)(bias_cat + 512);   // 65536
    unsigned short* Wpl = Wph + 65536;                         // 65536
    float* coef   = (float*)(Wpl + 65536);        // 24 (+pad)
    float4* S0    = (float4*)(coef + 32);         // n*2 float4
    int2* epack   = (int2*)(S0 + (size_t)n * 2);  // E
    int* cnt      = (int*)(epack + E);            // n
    int* row_ptr  = cnt + n;                      // n+1 (+1 pad)
    int* cursor   = row_ptr + n + 2;              // n
    int* bsum     = cursor + n;                   // B
    int* boff     = bsum + 256;                   // B
    float* gsums  = (float*)(boff + 256);         // G*128
    float* gcnt   = gsums + (size_t)G * HD;       // G

    const int* srcI = ei;
    const int* dstI = ei + E;

    hipMemsetAsync(cnt, 0, (size_t)n * sizeof(int), stream);
    hipMemsetAsync(gsums, 0, ((size_t)G * HD + G) * sizeof(float), stream);

    hist_kernel<<<(E + 255) / 256, 256, 0, stream>>>(dstI, cnt, E);
    scanA_kernel<<<B, 256, 0, stream>>>(cnt, row_ptr, bsum, n);
    scanB_kernel<<<1, 256, 0, stream>>>(bsum, boff, B);
    scanC_kernel<<<B, 256, 0, stream>>>(row_ptr, cursor, boff, n, E);
    scatter_kernel<<<(E + 255) / 256, 256, 0, stream>>>(dstI, srcI, eattr, cursor, epack, E);

    pack_kernel<<<256, 256, 0, stream>>>(l1_Wq, l1_Wk, l1_Wv, l1_Ws,
                                         l1_bq, l1_bk, l1_bv, l1_bs,
                                         Wph, Wpl, bias_cat);
    coef0_kernel<<<1, 128, 0, stream>>>(l0_Wq, l0_bq, l0_Wk, l0_bk, l0_We, coef);

    attn0a_kernel<<<(n + 255) / 256, 256, 0, stream>>>(
        x, coef, epack, row_ptr, S0, n);

    lin1_mfma<<<dim3((n + 127) / 128, 2), 256, 0, stream>>>(
        x, S0, l0_Wv, l0_bv, l0_We, l0_Ws, l0_bs,
        Wph, Wpl, bias_cat, qh, kvh, sh, n);
    attn_kernel<<<(n + 3) / 4, 256, 0, stream>>>(
        qh, kvh, sh, l1_We, epack, row_ptr, (__half2*)h1, n);

    pool_kernel<<<(n + 63) / 64, 128, 0, stream>>>(h1, batch, gsums, gcnt, n);
    cls_kernel<<<G, 128, 0, stream>>>(gsums, gcnt, cW1, cb1, cW2, cb2, (float*)d_out);
}